// Round 2
// baseline (779.547 us; speedup 1.0000x reference)
//
#include <hip/hip_runtime.h>

typedef unsigned short u16;
typedef unsigned int   u32;
typedef short bf16x8 __attribute__((ext_vector_type(8)));
typedef float f32x4  __attribute__((ext_vector_type(4)));

#define CAP 64  // bucket capacity per segment (E/N = 5 avg, Poisson max ~20; 64 is safe)

__device__ inline float b2f(u16 u){ return __builtin_bit_cast(float, (u32)u << 16); }
__device__ inline u16 f2b(float f){
  u32 x = __builtin_bit_cast(u32, f);
  x += 0x7fffu + ((x >> 16) & 1u);   // RNE; values here are never NaN
  return (u16)(x >> 16);
}
__device__ inline void up2(u32 u, float& lo, float& hi){
  lo = __builtin_bit_cast(float, u << 16);
  hi = __builtin_bit_cast(float, u & 0xffff0000u);
}
__device__ inline float celu3(float x){
  return x > 0.f ? x : 3.f * expm1f(x * (1.f/3.f));
}
__device__ inline float sigm(float x){ return 1.f / (1.f + expf(-x)); }

// ---------------------------------------------------------------------------
// K1: rotor precompute (fp32 in/out). fr[m][p][c], p in {0,1,2}, c in [0,32)
// fr[m][0] = rvn[2m+1]*rvn[2m], fr[m][1] = rvn[2m+1], fr[m][2] = identity
// (ETYPES=((0,2),(4,6)) only selects non-conjugated rv2 rows 0,2,4,6 = rv 0..3)
// ---------------------------------------------------------------------------
__global__ void fr_kernel(const float* __restrict__ rvec, float* __restrict__ fr){
  int c = threadIdx.x;
  if (c >= 32) return;
  for (int m = 0; m < 2; ++m){
    float ar = rvec[(2*m)*64 + c*2],   ai = rvec[(2*m)*64 + c*2 + 1];
    float br = rvec[(2*m+1)*64 + c*2], bi = rvec[(2*m+1)*64 + c*2 + 1];
    float na = rsqrtf(ar*ar + ai*ai); ar *= na; ai *= na;
    float nb = rsqrtf(br*br + bi*bi); br *= nb; bi *= nb;
    float* f = fr + m*192;
    f[c*2]        = br*ar - bi*ai;   // p=0 (composed rotor)
    f[c*2 + 1]    = br*ai + bi*ar;
    f[64 + c*2]   = br;              // p=1
    f[64 + c*2+1] = bi;
    f[128 + c*2]  = 1.f;             // p=2 identity
    f[128 + c*2+1]= 0.f;
  }
}

// ---------------------------------------------------------------------------
// K2: per-edge: eft (bf16, 64/edge), a (fp32 x heads), bucket build
// ---------------------------------------------------------------------------
__global__ __launch_bounds__(256) void edge_kernel(
    const float* __restrict__ feat, const int* __restrict__ inst,
    const float* __restrict__ fr, const float* __restrict__ attn1,
    const float* __restrict__ attn2, u16* __restrict__ eft,
    float* __restrict__ a_ws, int* __restrict__ cnt, int* __restrict__ bucket,
    int E, int N)
{
  __shared__ float frs[192];
  __shared__ float w1s[256];
  __shared__ float w2s[256];
  int m = blockIdx.y;
  int t = threadIdx.x;
  if (t < 192) frs[t] = fr[m*192 + t];
  w1s[t] = attn1[t];
  w2s[t] = attn2[t];
  __syncthreads();

  int e = blockIdx.x * 256 + t;
  if (e >= E) return;
  int base = m*E + e;
  int i0 = inst[base*3], i1 = inst[base*3 + 1], i2 = inst[base*3 + 2];

  const float4* r0 = (const float4*)feat + (size_t)i0 * 16;  // 64 floats/row
  const float4* r1 = (const float4*)feat + (size_t)i1 * 16;
  const float4* r2 = (const float4*)feat + (size_t)i2 * 16;
  ushort4* eo = (ushort4*)eft + (size_t)base * 16;           // 64 bf16/edge

  float d1[4] = {0.f,0.f,0.f,0.f};
  float d2[4] = {0.f,0.f,0.f,0.f};

  #pragma unroll
  for (int ch = 0; ch < 16; ++ch){
    float4 x0 = r0[ch], x1 = r1[ch], x2 = r2[ch];   // elements ch*4 .. ch*4+3
    float ef[4];
    #pragma unroll
    for (int p = 0; p < 2; ++p){                    // complex pair c = ch*2+p
      int c = ch*2 + p;
      float R0r = frs[2*c],      R0i = frs[2*c + 1];
      float R1r = frs[64 + 2*c], R1i = frs[64 + 2*c + 1];
      float F0r = p ? x0.z : x0.x, F0i = p ? x0.w : x0.y;
      float F1r = p ? x1.z : x1.x, F1i = p ? x1.w : x1.y;
      float F2r = p ? x2.z : x2.x, F2i = p ? x2.w : x2.y;
      float mre = (F0r*R0r - F0i*R0i + F1r*R1r - F1i*R1i + F2r) * (1.f/3.f);
      float mim = (F0r*R0i + F0i*R0r + F1r*R1i + F1i*R1r + F2i) * (1.f/3.f);
      float s;
      s = celu3(mre) * sigm(mre); ef[2*p]   = celu3(s);
      s = celu3(mim) * sigm(mim); ef[2*p+1] = celu3(s);
    }
    ushort4 uo;
    uo.x = f2b(ef[0]); uo.y = f2b(ef[1]); uo.z = f2b(ef[2]); uo.w = f2b(ef[3]);
    eo[ch] = uo;

    #pragma unroll
    for (int k = 0; k < 4; ++k){
      int wb = k*64 + ch*4;
      d1[k] += x0.x*w1s[wb] + x0.y*w1s[wb+1] + x0.z*w1s[wb+2] + x0.w*w1s[wb+3];
      d2[k] += ef[0]*w2s[wb] + ef[1]*w2s[wb+1] + ef[2]*w2s[wb+2] + ef[3]*w2s[wb+3];
    }
  }
  float4 av;
  av.x = celu3(celu3(d1[0]) + d2[0]);
  av.y = celu3(celu3(d1[1]) + d2[1]);
  av.z = celu3(celu3(d1[2]) + d2[2]);
  av.w = celu3(celu3(d1[3]) + d2[3]);
  ((float4*)a_ws)[base] = av;

  int pos = atomicAdd(&cnt[m*N + i0], 1);
  if (pos < CAP) bucket[(size_t)(m*N + i0)*CAP + pos] = e;
}

// ---------------------------------------------------------------------------
// K3: one wave per (segment, path): exact two-pass softmax over the bucket,
// z[n,k,h] = celu3(sum attn*eft) -> bf16
// ---------------------------------------------------------------------------
__global__ __launch_bounds__(256) void seg_kernel(
    const float* __restrict__ a_ws, const u16* __restrict__ eft,
    const int* __restrict__ cnt, const int* __restrict__ bucket,
    u16* __restrict__ z, int E, int N)
{
  int m = blockIdx.y;
  int n = blockIdx.x * 4 + (threadIdx.x >> 6);
  if (n >= N) return;
  int lane = threadIdx.x & 63;
  int sidx = m*N + n;
  int deg = cnt[sidx]; if (deg > CAP) deg = CAP;

  float h0=0.f, h1=0.f, h2=0.f, h3=0.f;
  if (deg > 0){
    const int* bk = bucket + (size_t)sidx * CAP;
    const float4* ap = (const float4*)a_ws;
    size_t ebase = (size_t)m * E;
    float m0=-1e30f, m1=-1e30f, m2=-1e30f, m3=-1e30f;
    for (int j = 0; j < deg; ++j){
      float4 av = ap[ebase + bk[j]];
      m0 = fmaxf(m0, av.x); m1 = fmaxf(m1, av.y);
      m2 = fmaxf(m2, av.z); m3 = fmaxf(m3, av.w);
    }
    float d0=0.f, d1=0.f, d2=0.f, d3=0.f;
    for (int j = 0; j < deg; ++j){
      int e = bk[j];
      float4 av = ap[ebase + e];
      float w0 = expf(av.x - m0), w1 = expf(av.y - m1);
      float w2 = expf(av.z - m2), w3 = expf(av.w - m3);
      d0 += w0; d1 += w1; d2 += w2; d3 += w3;
      float ev = b2f(eft[(ebase + e)*64 + lane]);
      h0 += w0*ev; h1 += w1*ev; h2 += w2*ev; h3 += w3*ev;
    }
    h0 /= d0; h1 /= d1; h2 /= d2; h3 /= d3;   // d >= 1 always (max is in bucket)
  }
  u16* zr = z + (size_t)sidx*256 + lane;
  zr[0]   = f2b(celu3(h0));
  zr[64]  = f2b(celu3(h1));
  zr[128] = f2b(celu3(h2));
  zr[192] = f2b(celu3(h3));
}

// ---------------------------------------------------------------------------
// K4: fused 3-layer MLP (MFMA bf16), 64 rows/block; accumulates sum(t@fw3) per path
// ---------------------------------------------------------------------------
__global__ __launch_bounds__(256) void mlp_kernel(
    const u16* __restrict__ z, const float* __restrict__ fw1, const float* __restrict__ fb1,
    const float* __restrict__ fw2, const float* __restrict__ fb2, const float* __restrict__ fw3,
    float* __restrict__ wacc, int rows, int N)
{
  __shared__ u16 buf[64][264];   // z tile then t1 tile; stride 264 keeps 16B rows
  __shared__ u16 t2t[64][136];
  __shared__ float sArr[64];
  int tid = threadIdx.x;
  int row0 = blockIdx.x * 64;

  // stage z (bf16 global) -> LDS; rows past `rows` zeroed
  const uint4* zg = (const uint4*)z;     // 8 bf16 per uint4, 32 per row
  #pragma unroll
  for (int it = 0; it < 8; ++it){
    int idx = it*256 + tid;
    int row = idx >> 5;
    int c8  = idx & 31;
    uint4 v = make_uint4(0u,0u,0u,0u);
    int gr = row0 + row;
    if (gr < rows) v = zg[(size_t)gr*32 + c8];
    *(uint4*)&buf[row][c8*8] = v;
  }
  __syncthreads();

  int wv = tid >> 6, lane = tid & 63, lr = lane & 15, quad = lane >> 4;
  f32x4 zero4 = {0.f, 0.f, 0.f, 0.f};

  // ---- layer 1: t1(64x256) = celu3(z @ fw1^T + fb1); wave wv owns cols [64wv,64wv+64)
  f32x4 acc[4][4];
  #pragma unroll
  for (int a = 0; a < 4; ++a)
    #pragma unroll
    for (int b = 0; b < 4; ++b) acc[a][b] = zero4;
  #pragma unroll
  for (int ks = 0; ks < 8; ++ks){
    int kb = ks*32 + quad*8;
    bf16x8 af[4], bfr[4];
    #pragma unroll
    for (int mt = 0; mt < 4; ++mt) af[mt] = *(const bf16x8*)&buf[mt*16 + lr][kb];
    #pragma unroll
    for (int nt = 0; nt < 4; ++nt){
      const float4* wp = (const float4*)(fw1 + (size_t)(wv*64 + nt*16 + lr)*256 + kb);
      float4 wa = wp[0], wb = wp[1];
      bf16x8 bb;
      bb[0]=(short)f2b(wa.x); bb[1]=(short)f2b(wa.y); bb[2]=(short)f2b(wa.z); bb[3]=(short)f2b(wa.w);
      bb[4]=(short)f2b(wb.x); bb[5]=(short)f2b(wb.y); bb[6]=(short)f2b(wb.z); bb[7]=(short)f2b(wb.w);
      bfr[nt] = bb;
    }
    #pragma unroll
    for (int mt = 0; mt < 4; ++mt)
      #pragma unroll
      for (int nt = 0; nt < 4; ++nt)
        acc[mt][nt] = __builtin_amdgcn_mfma_f32_16x16x32_bf16(af[mt], bfr[nt], acc[mt][nt], 0, 0, 0);
  }
  __syncthreads();   // all z reads done before overwriting buf with t1
  #pragma unroll
  for (int nt = 0; nt < 4; ++nt){
    int col = wv*64 + nt*16 + lr;
    float bias = fb1[col];
    #pragma unroll
    for (int mt = 0; mt < 4; ++mt)
      #pragma unroll
      for (int ri = 0; ri < 4; ++ri){
        int row = mt*16 + quad*4 + ri;      // C/D: col=lane&15, row=(lane>>4)*4+reg
        buf[row][col] = f2b(celu3(acc[mt][nt][ri] + bias));
      }
  }
  __syncthreads();

  // ---- layer 2: t2(64x128) = celu3(t1 @ fw2^T + fb2); wave wv owns cols [32wv,32wv+32)
  f32x4 acc2[4][2];
  #pragma unroll
  for (int a = 0; a < 4; ++a){ acc2[a][0] = zero4; acc2[a][1] = zero4; }
  #pragma unroll
  for (int ks = 0; ks < 8; ++ks){
    int kb = ks*32 + quad*8;
    bf16x8 af[4], bfr[2];
    #pragma unroll
    for (int mt = 0; mt < 4; ++mt) af[mt] = *(const bf16x8*)&buf[mt*16 + lr][kb];
    #pragma unroll
    for (int nt = 0; nt < 2; ++nt){
      const float4* wp = (const float4*)(fw2 + (size_t)(wv*32 + nt*16 + lr)*256 + kb);
      float4 wa = wp[0], wb = wp[1];
      bf16x8 bb;
      bb[0]=(short)f2b(wa.x); bb[1]=(short)f2b(wa.y); bb[2]=(short)f2b(wa.z); bb[3]=(short)f2b(wa.w);
      bb[4]=(short)f2b(wb.x); bb[5]=(short)f2b(wb.y); bb[6]=(short)f2b(wb.z); bb[7]=(short)f2b(wb.w);
      bfr[nt] = bb;
    }
    #pragma unroll
    for (int mt = 0; mt < 4; ++mt)
      #pragma unroll
      for (int nt = 0; nt < 2; ++nt)
        acc2[mt][nt] = __builtin_amdgcn_mfma_f32_16x16x32_bf16(af[mt], bfr[nt], acc2[mt][nt], 0, 0, 0);
  }
  #pragma unroll
  for (int nt = 0; nt < 2; ++nt){
    int col = wv*32 + nt*16 + lr;
    float bias = fb2[col];
    #pragma unroll
    for (int mt = 0; mt < 4; ++mt)
      #pragma unroll
      for (int ri = 0; ri < 4; ++ri)
        t2t[mt*16 + quad*4 + ri][col] = f2b(celu3(acc2[mt][nt][ri] + bias));
  }
  __syncthreads();

  // ---- layer 3: s_r = t2[r,:] . fw3 ; 4 threads per row
  int r = tid >> 2, q = tid & 3;
  float p = 0.f;
  #pragma unroll
  for (int j = 0; j < 32; ++j){
    int jj = q*32 + j;
    p += b2f(t2t[r][jj]) * fw3[jj];
  }
  p += __shfl_xor(p, 1);
  p += __shfl_xor(p, 2);
  if (q == 0) sArr[r] = p;
  __syncthreads();

  if (tid < 64){
    int gr = row0 + tid;
    float s  = (gr < rows) ? sArr[tid] : 0.f;
    float s0 = (gr < N) ? s : 0.f;      // path-0 rows are sidx < N
    float s1 = (gr < N) ? 0.f : s;
    #pragma unroll
    for (int off = 32; off; off >>= 1){
      s0 += __shfl_xor(s0, off);
      s1 += __shfl_xor(s1, off);
    }
    if (tid == 0){
      atomicAdd(&wacc[0], s0);
      atomicAdd(&wacc[1], s1);
    }
  }
}

// ---------------------------------------------------------------------------
// K5a: beta = softmax(w / N) over the 2 paths
// ---------------------------------------------------------------------------
__global__ void beta_kernel(float* __restrict__ wacc, float invN){
  if (threadIdx.x == 0 && blockIdx.x == 0){
    float w0 = wacc[0]*invN, w1 = wacc[1]*invN;
    float mx = fmaxf(w0, w1);
    float e0 = expf(w0 - mx), e1 = expf(w1 - mx);
    float s = e0 + e1;
    wacc[2] = e0 / s;
    wacc[3] = e1 / s;
  }
}

// ---------------------------------------------------------------------------
// K5b: out = beta0*z0 + beta1*z1 -> fp32
// ---------------------------------------------------------------------------
__global__ __launch_bounds__(256) void out_kernel(
    const u16* __restrict__ z, const float* __restrict__ wacc,
    float* __restrict__ out, int total)   // total = N*256
{
  int idx = blockIdx.x * 256 + threadIdx.x;   // one uint4 (8 bf16) per thread
  if (idx*8 >= total) return;
  float b0 = wacc[2], b1 = wacc[3];
  uint4 u0 = ((const uint4*)z)[idx];
  uint4 u1 = ((const uint4*)z)[(total >> 3) + idx];
  float a0,a1v,c0,c1;
  float4 o;
  up2(u0.x, a0, a1v); up2(u1.x, c0, c1);
  o.x = b0*a0 + b1*c0; o.y = b0*a1v + b1*c1;
  up2(u0.y, a0, a1v); up2(u1.y, c0, c1);
  o.z = b0*a0 + b1*c0; o.w = b0*a1v + b1*c1;
  ((float4*)out)[idx*2] = o;
  up2(u0.z, a0, a1v); up2(u1.z, c0, c1);
  o.x = b0*a0 + b1*c0; o.y = b0*a1v + b1*c1;
  up2(u0.w, a0, a1v); up2(u1.w, c0, c1);
  o.z = b0*a0 + b1*c0; o.w = b0*a1v + b1*c1;
  ((float4*)out)[idx*2 + 1] = o;
}

// ---------------------------------------------------------------------------
extern "C" void kernel_launch(void* const* d_in, const int* in_sizes, int n_in,
                              void* d_out, int out_size, void* d_ws, size_t ws_size,
                              hipStream_t stream)
{
  (void)n_in; (void)out_size; (void)ws_size;
  const float* feat  = (const float*)d_in[0];
  const float* rvec  = (const float*)d_in[1];
  const float* attn1 = (const float*)d_in[2];
  const float* attn2 = (const float*)d_in[3];
  const float* fw1   = (const float*)d_in[4];
  const float* fb1   = (const float*)d_in[5];
  const float* fw2   = (const float*)d_in[6];
  const float* fb2   = (const float*)d_in[7];
  const float* fw3   = (const float*)d_in[8];
  const int*   inst  = (const int*)d_in[9];

  int N = in_sizes[0] / 64;       // 50000
  int E = in_sizes[9] / 6;        // 250000

  char* ws = (char*)d_ws;
  u16*   z      = (u16*)ws;                            size_t zB = (size_t)2*N*256*2;
  u16*   eft    = (u16*)(ws + zB);                     size_t eB = (size_t)2*E*64*2;
  float* a_ws   = (float*)(ws + zB + eB);              size_t aB = (size_t)2*E*4*4;
  int*   bucket = (int*)(ws + zB + eB + aB);           size_t bB = (size_t)2*N*CAP*4;
  int*   cnt    = (int*)(ws + zB + eB + aB + bB);      size_t cB = (size_t)2*N*4;
  float* fr     = (float*)(ws + zB + eB + aB + bB + cB);
  float* wacc   = fr + 384;

  hipMemsetAsync(cnt, 0, cB, stream);
  hipMemsetAsync(wacc, 0, 2*sizeof(float), stream);

  fr_kernel<<<1, 64, 0, stream>>>(rvec, fr);
  edge_kernel<<<dim3((E + 255)/256, 2), 256, 0, stream>>>(
      feat, inst, fr, attn1, attn2, eft, a_ws, cnt, bucket, E, N);
  seg_kernel<<<dim3((N + 3)/4, 2), 256, 0, stream>>>(a_ws, eft, cnt, bucket, z, E, N);
  mlp_kernel<<<(2*N + 63)/64, 256, 0, stream>>>(z, fw1, fb1, fw2, fb2, fw3, wacc, 2*N, N);
  beta_kernel<<<1, 64, 0, stream>>>(wacc, 1.f/(float)N);
  out_kernel<<<((N*256/8) + 255)/256, 256, 0, stream>>>(z, wacc, (float*)d_out, N*256);
}

// Round 3
// 452.511 us; speedup vs baseline: 1.7227x; 1.7227x over previous
//
#include <hip/hip_runtime.h>

typedef unsigned short u16;
typedef unsigned int   u32;
typedef short bf16x8 __attribute__((ext_vector_type(8)));
typedef float f32x4  __attribute__((ext_vector_type(4)));

#define CAP 64  // bucket capacity per segment (E/N = 5 avg; Poisson tail << 64)

__device__ inline float b2f(u16 u){ return __builtin_bit_cast(float, (u32)u << 16); }
__device__ inline u16 f2b(float f){
  u32 x = __builtin_bit_cast(u32, f);
  x += 0x7fffu + ((x >> 16) & 1u);   // RNE; values here are never NaN
  return (u16)(x >> 16);
}
__device__ inline void up2(u32 u, float& lo, float& hi){
  lo = __builtin_bit_cast(float, u << 16);
  hi = __builtin_bit_cast(float, u & 0xffff0000u);
}
__device__ inline float celu3(float x){
  return x > 0.f ? x : 3.f * expm1f(x * (1.f/3.f));
}
__device__ inline float sigm(float x){ return 1.f / (1.f + expf(-x)); }

// ---------------------------------------------------------------------------
// K0: fp32 -> bf16 pack, 8 elements/thread
// ---------------------------------------------------------------------------
__global__ __launch_bounds__(256) void conv_kernel(
    const float* __restrict__ src, u16* __restrict__ dst, int n8)
{
  int i = blockIdx.x * 256 + threadIdx.x;
  if (i >= n8) return;
  float4 a = ((const float4*)src)[2*i], b = ((const float4*)src)[2*i + 1];
  uint4 o;
  o.x = (u32)f2b(a.x) | ((u32)f2b(a.y) << 16);
  o.y = (u32)f2b(a.z) | ((u32)f2b(a.w) << 16);
  o.z = (u32)f2b(b.x) | ((u32)f2b(b.y) << 16);
  o.w = (u32)f2b(b.z) | ((u32)f2b(b.w) << 16);
  ((uint4*)dst)[i] = o;
}

// ---------------------------------------------------------------------------
// K1: rotor precompute (fp32). fr[m][p][c], p in {0,1}; p=2 is identity (implicit)
// fr[m][0] = rvn[2m+1]*rvn[2m], fr[m][1] = rvn[2m+1]
// (ETYPES=((0,2),(4,6)) selects only non-conjugated rv2 rows 0,2,4,6 = rv 0..3)
// ---------------------------------------------------------------------------
__global__ void fr_kernel(const float* __restrict__ rvec, float* __restrict__ fr){
  int c = threadIdx.x;
  if (c >= 32) return;
  for (int m = 0; m < 2; ++m){
    float ar = rvec[(2*m)*64 + c*2],   ai = rvec[(2*m)*64 + c*2 + 1];
    float br = rvec[(2*m+1)*64 + c*2], bi = rvec[(2*m+1)*64 + c*2 + 1];
    float na = rsqrtf(ar*ar + ai*ai); ar *= na; ai *= na;
    float nb = rsqrtf(br*br + bi*bi); br *= nb; bi *= nb;
    float* f = fr + m*128;
    f[c*2]        = br*ar - bi*ai;   // p=0 (composed rotor)
    f[c*2 + 1]    = br*ai + bi*ar;
    f[64 + c*2]   = br;              // p=1
    f[64 + c*2+1] = bi;
  }
}

// ---------------------------------------------------------------------------
// K2: per-edge, 16 lanes/edge. Coalesced bf16 row gathers, full-line eft
// stores, shfl-reduced attention dots, bucket build.
// ---------------------------------------------------------------------------
__global__ __launch_bounds__(256) void edge_kernel(
    const u16* __restrict__ featb, const int* __restrict__ inst,
    const float* __restrict__ fr, const float* __restrict__ attn1,
    const float* __restrict__ attn2, u16* __restrict__ eft,
    float* __restrict__ a_ws, int* __restrict__ cnt, int* __restrict__ bucket,
    int E, int N)
{
  __shared__ float frs[128];
  __shared__ float w1s[256];
  __shared__ float w2s[256];
  int m = blockIdx.y;
  int t = threadIdx.x;
  if (t < 128) frs[t] = fr[m*128 + t];
  w1s[t] = attn1[t];
  w2s[t] = attn2[t];
  __syncthreads();

  int g = t >> 4, l = t & 15;           // group = edge, lane-in-group = 4 channels
  int e = blockIdx.x * 16 + g;
  if (e >= E) return;
  int base = (m*E + e)*3;
  int i0 = inst[base], i1 = inst[base+1], i2 = inst[base+2];

  const uint2* fb = (const uint2*)featb;             // 4 bf16 per uint2, 16/row
  uint2 v0 = fb[(size_t)i0*16 + l];
  uint2 v1 = fb[(size_t)i1*16 + l];
  uint2 v2 = fb[(size_t)i2*16 + l];
  float f0[4], f1[4], f2v[4];
  up2(v0.x, f0[0], f0[1]); up2(v0.y, f0[2], f0[3]);
  up2(v1.x, f1[0], f1[1]); up2(v1.y, f1[2], f1[3]);
  up2(v2.x, f2v[0], f2v[1]); up2(v2.y, f2v[2], f2v[3]);

  float4 R0 = *(const float4*)&frs[4*l];        // (Re c0, Im c0, Re c1, Im c1)
  float4 R1 = *(const float4*)&frs[64 + 4*l];

  float mre0 = (f0[0]*R0.x - f0[1]*R0.y + f1[0]*R1.x - f1[1]*R1.y + f2v[0]) * (1.f/3.f);
  float mim0 = (f0[0]*R0.y + f0[1]*R0.x + f1[0]*R1.y + f1[1]*R1.x + f2v[1]) * (1.f/3.f);
  float mre1 = (f0[2]*R0.z - f0[3]*R0.w + f1[2]*R1.z - f1[3]*R1.w + f2v[2]) * (1.f/3.f);
  float mim1 = (f0[2]*R0.w + f0[3]*R0.z + f1[2]*R1.w + f1[3]*R1.z + f2v[3]) * (1.f/3.f);

  float ef[4], s;
  s = celu3(mre0) * sigm(mre0); ef[0] = celu3(s);
  s = celu3(mim0) * sigm(mim0); ef[1] = celu3(s);
  s = celu3(mre1) * sigm(mre1); ef[2] = celu3(s);
  s = celu3(mim1) * sigm(mim1); ef[3] = celu3(s);

  ushort4 uo;
  uo.x = f2b(ef[0]); uo.y = f2b(ef[1]); uo.z = f2b(ef[2]); uo.w = f2b(ef[3]);
  ((ushort4*)eft)[(size_t)(m*E + e)*16 + l] = uo;   // wave: 4 edges x 128B contiguous

  float d1[4], d2[4];
  #pragma unroll
  for (int k = 0; k < 4; ++k){
    int wb = k*64 + l*4;
    d1[k] = f0[0]*w1s[wb] + f0[1]*w1s[wb+1] + f0[2]*w1s[wb+2] + f0[3]*w1s[wb+3];
    d2[k] = ef[0]*w2s[wb] + ef[1]*w2s[wb+1] + ef[2]*w2s[wb+2] + ef[3]*w2s[wb+3];
  }
  #pragma unroll
  for (int off = 8; off; off >>= 1){
    #pragma unroll
    for (int k = 0; k < 4; ++k){
      d1[k] += __shfl_xor(d1[k], off);
      d2[k] += __shfl_xor(d2[k], off);
    }
  }
  if (l == 0){
    float4 av;
    av.x = celu3(celu3(d1[0]) + d2[0]);
    av.y = celu3(celu3(d1[1]) + d2[1]);
    av.z = celu3(celu3(d1[2]) + d2[2]);
    av.w = celu3(celu3(d1[3]) + d2[3]);
    ((float4*)a_ws)[m*E + e] = av;
    int pos = atomicAdd(&cnt[m*N + i0], 1);
    if (pos < CAP) bucket[(size_t)(m*N + i0)*CAP + pos] = e;
  }
}

// ---------------------------------------------------------------------------
// K3: one wave per (segment, path): exact two-pass softmax over the bucket,
// z[n,k,h] = celu3(sum attn*eft) -> bf16
// ---------------------------------------------------------------------------
__global__ __launch_bounds__(256) void seg_kernel(
    const float* __restrict__ a_ws, const u16* __restrict__ eft,
    const int* __restrict__ cnt, const int* __restrict__ bucket,
    u16* __restrict__ z, int E, int N)
{
  int m = blockIdx.y;
  int n = blockIdx.x * 4 + (threadIdx.x >> 6);
  if (n >= N) return;
  int lane = threadIdx.x & 63;
  int sidx = m*N + n;
  int deg = cnt[sidx]; if (deg > CAP) deg = CAP;

  float h0=0.f, h1=0.f, h2=0.f, h3=0.f;
  if (deg > 0){
    const int* bk = bucket + (size_t)sidx * CAP;
    const float4* ap = (const float4*)a_ws;
    size_t ebase = (size_t)m * E;
    float m0=-1e30f, m1=-1e30f, m2=-1e30f, m3=-1e30f;
    for (int j = 0; j < deg; ++j){
      float4 av = ap[ebase + bk[j]];
      m0 = fmaxf(m0, av.x); m1 = fmaxf(m1, av.y);
      m2 = fmaxf(m2, av.z); m3 = fmaxf(m3, av.w);
    }
    float d0=0.f, d1=0.f, d2=0.f, d3=0.f;
    for (int j = 0; j < deg; ++j){
      int e = bk[j];
      float4 av = ap[ebase + e];
      float w0 = expf(av.x - m0), w1 = expf(av.y - m1);
      float w2 = expf(av.z - m2), w3 = expf(av.w - m3);
      d0 += w0; d1 += w1; d2 += w2; d3 += w3;
      float ev = b2f(eft[(ebase + e)*64 + lane]);
      h0 += w0*ev; h1 += w1*ev; h2 += w2*ev; h3 += w3*ev;
    }
    h0 /= d0; h1 /= d1; h2 /= d2; h3 /= d3;   // d >= 1 (max is in bucket)
  }
  u16* zr = z + (size_t)sidx*256 + lane;
  zr[0]   = f2b(celu3(h0));
  zr[64]  = f2b(celu3(h1));
  zr[128] = f2b(celu3(h2));
  zr[192] = f2b(celu3(h3));
}

// ---------------------------------------------------------------------------
// K4: fused 3-layer MLP (MFMA bf16), 64 rows/block; accumulates sum(t@fw3) per path
// ---------------------------------------------------------------------------
__global__ __launch_bounds__(256) void mlp_kernel(
    const u16* __restrict__ z, const u16* __restrict__ fw1b, const float* __restrict__ fb1,
    const u16* __restrict__ fw2b, const float* __restrict__ fb2, const float* __restrict__ fw3,
    float* __restrict__ wacc, int rows, int N)
{
  __shared__ u16 buf[64][264];   // z tile then t1 tile; stride 264 keeps 16B rows
  __shared__ u16 t2t[64][136];
  __shared__ float sArr[64];
  int tid = threadIdx.x;
  int row0 = blockIdx.x * 64;

  // stage z (bf16 global) -> LDS; rows past `rows` zeroed
  const uint4* zg = (const uint4*)z;     // 8 bf16 per uint4, 32 per row
  #pragma unroll
  for (int it = 0; it < 8; ++it){
    int idx = it*256 + tid;
    int row = idx >> 5;
    int c8  = idx & 31;
    uint4 v = make_uint4(0u,0u,0u,0u);
    int gr = row0 + row;
    if (gr < rows) v = zg[(size_t)gr*32 + c8];
    *(uint4*)&buf[row][c8*8] = v;
  }
  __syncthreads();

  int wv = tid >> 6, lane = tid & 63, lr = lane & 15, quad = lane >> 4;
  f32x4 zero4 = {0.f, 0.f, 0.f, 0.f};

  // ---- layer 1: t1(64x256) = celu3(z @ fw1^T + fb1); wave wv owns cols [64wv,64wv+64)
  f32x4 acc[4][4];
  #pragma unroll
  for (int a = 0; a < 4; ++a)
    #pragma unroll
    for (int b = 0; b < 4; ++b) acc[a][b] = zero4;
  #pragma unroll
  for (int ks = 0; ks < 8; ++ks){
    int kb = ks*32 + quad*8;
    bf16x8 af[4], bfr[4];
    #pragma unroll
    for (int mt = 0; mt < 4; ++mt) af[mt] = *(const bf16x8*)&buf[mt*16 + lr][kb];
    #pragma unroll
    for (int nt = 0; nt < 4; ++nt)
      bfr[nt] = *(const bf16x8*)(fw1b + (size_t)(wv*64 + nt*16 + lr)*256 + kb);
    #pragma unroll
    for (int mt = 0; mt < 4; ++mt)
      #pragma unroll
      for (int nt = 0; nt < 4; ++nt)
        acc[mt][nt] = __builtin_amdgcn_mfma_f32_16x16x32_bf16(af[mt], bfr[nt], acc[mt][nt], 0, 0, 0);
  }
  __syncthreads();   // all z reads done before overwriting buf with t1
  #pragma unroll
  for (int nt = 0; nt < 4; ++nt){
    int col = wv*64 + nt*16 + lr;
    float bias = fb1[col];
    #pragma unroll
    for (int mt = 0; mt < 4; ++mt)
      #pragma unroll
      for (int ri = 0; ri < 4; ++ri){
        int row = mt*16 + quad*4 + ri;      // C/D: col=lane&15, row=(lane>>4)*4+reg
        buf[row][col] = f2b(celu3(acc[mt][nt][ri] + bias));
      }
  }
  __syncthreads();

  // ---- layer 2: t2(64x128) = celu3(t1 @ fw2^T + fb2); wave wv owns cols [32wv,32wv+32)
  f32x4 acc2[4][2];
  #pragma unroll
  for (int a = 0; a < 4; ++a){ acc2[a][0] = zero4; acc2[a][1] = zero4; }
  #pragma unroll
  for (int ks = 0; ks < 8; ++ks){
    int kb = ks*32 + quad*8;
    bf16x8 af[4], bfr[2];
    #pragma unroll
    for (int mt = 0; mt < 4; ++mt) af[mt] = *(const bf16x8*)&buf[mt*16 + lr][kb];
    #pragma unroll
    for (int nt = 0; nt < 2; ++nt)
      bfr[nt] = *(const bf16x8*)(fw2b + (size_t)(wv*32 + nt*16 + lr)*256 + kb);
    #pragma unroll
    for (int mt = 0; mt < 4; ++mt)
      #pragma unroll
      for (int nt = 0; nt < 2; ++nt)
        acc2[mt][nt] = __builtin_amdgcn_mfma_f32_16x16x32_bf16(af[mt], bfr[nt], acc2[mt][nt], 0, 0, 0);
  }
  #pragma unroll
  for (int nt = 0; nt < 2; ++nt){
    int col = wv*32 + nt*16 + lr;
    float bias = fb2[col];
    #pragma unroll
    for (int mt = 0; mt < 4; ++mt)
      #pragma unroll
      for (int ri = 0; ri < 4; ++ri)
        t2t[mt*16 + quad*4 + ri][col] = f2b(celu3(acc2[mt][nt][ri] + bias));
  }
  __syncthreads();

  // ---- layer 3: s_r = t2[r,:] . fw3 ; 4 threads per row
  int r = tid >> 2, q = tid & 3;
  float p = 0.f;
  #pragma unroll
  for (int j = 0; j < 32; ++j){
    int jj = q*32 + j;
    p += b2f(t2t[r][jj]) * fw3[jj];
  }
  p += __shfl_xor(p, 1);
  p += __shfl_xor(p, 2);
  if (q == 0) sArr[r] = p;
  __syncthreads();

  if (tid < 64){
    int gr = row0 + tid;
    float s  = (gr < rows) ? sArr[tid] : 0.f;
    float s0 = (gr < N) ? s : 0.f;      // path-0 rows are sidx < N
    float s1 = (gr < N) ? 0.f : s;
    #pragma unroll
    for (int off = 32; off; off >>= 1){
      s0 += __shfl_xor(s0, off);
      s1 += __shfl_xor(s1, off);
    }
    if (tid == 0){
      atomicAdd(&wacc[0], s0);
      atomicAdd(&wacc[1], s1);
    }
  }
}

// ---------------------------------------------------------------------------
// K5a: beta = softmax(w / N) over the 2 paths
// ---------------------------------------------------------------------------
__global__ void beta_kernel(float* __restrict__ wacc, float invN){
  if (threadIdx.x == 0 && blockIdx.x == 0){
    float w0 = wacc[0]*invN, w1 = wacc[1]*invN;
    float mx = fmaxf(w0, w1);
    float e0 = expf(w0 - mx), e1 = expf(w1 - mx);
    float s = e0 + e1;
    wacc[2] = e0 / s;
    wacc[3] = e1 / s;
  }
}

// ---------------------------------------------------------------------------
// K5b: out = beta0*z0 + beta1*z1 -> fp32
// ---------------------------------------------------------------------------
__global__ __launch_bounds__(256) void out_kernel(
    const u16* __restrict__ z, const float* __restrict__ wacc,
    float* __restrict__ out, int total)   // total = N*256
{
  int idx = blockIdx.x * 256 + threadIdx.x;   // one uint4 (8 bf16) per thread
  if (idx*8 >= total) return;
  float b0 = wacc[2], b1 = wacc[3];
  uint4 u0 = ((const uint4*)z)[idx];
  uint4 u1 = ((const uint4*)z)[(total >> 3) + idx];
  float a0,a1v,c0,c1;
  float4 o;
  up2(u0.x, a0, a1v); up2(u1.x, c0, c1);
  o.x = b0*a0 + b1*c0; o.y = b0*a1v + b1*c1;
  up2(u0.y, a0, a1v); up2(u1.y, c0, c1);
  o.z = b0*a0 + b1*c0; o.w = b0*a1v + b1*c1;
  ((float4*)out)[idx*2] = o;
  up2(u0.z, a0, a1v); up2(u1.z, c0, c1);
  o.x = b0*a0 + b1*c0; o.y = b0*a1v + b1*c1;
  up2(u0.w, a0, a1v); up2(u1.w, c0, c1);
  o.z = b0*a0 + b1*c0; o.w = b0*a1v + b1*c1;
  ((float4*)out)[idx*2 + 1] = o;
}

// ---------------------------------------------------------------------------
extern "C" void kernel_launch(void* const* d_in, const int* in_sizes, int n_in,
                              void* d_out, int out_size, void* d_ws, size_t ws_size,
                              hipStream_t stream)
{
  (void)n_in; (void)out_size; (void)ws_size;
  const float* feat  = (const float*)d_in[0];
  const float* rvec  = (const float*)d_in[1];
  const float* attn1 = (const float*)d_in[2];
  const float* attn2 = (const float*)d_in[3];
  const float* fw1   = (const float*)d_in[4];
  const float* fb1   = (const float*)d_in[5];
  const float* fw2   = (const float*)d_in[6];
  const float* fb2   = (const float*)d_in[7];
  const float* fw3   = (const float*)d_in[8];
  const int*   inst  = (const int*)d_in[9];

  int N = in_sizes[0] / 64;       // 50000
  int E = in_sizes[9] / 6;        // 250000

  char* ws = (char*)d_ws;
  u16*   z      = (u16*)ws;                            size_t zB = (size_t)2*N*256*2;
  u16*   eft    = (u16*)(ws + zB);                     size_t eB = (size_t)2*E*64*2;
  float* a_ws   = (float*)(ws + zB + eB);              size_t aB = (size_t)2*E*4*4;
  int*   bucket = (int*)(ws + zB + eB + aB);           size_t bB = (size_t)2*N*CAP*4;
  int*   cnt    = (int*)(ws + zB + eB + aB + bB);      size_t cB = (size_t)2*N*4;
  u16*   featb  = (u16*)(ws + zB + eB + aB + bB + cB); size_t fB = (size_t)N*64*2;
  u16*   fw1b   = (u16*)(ws + zB + eB + aB + bB + cB + fB);
  u16*   fw2b   = fw1b + 256*256;
  float* fr     = (float*)(fw2b + 128*256);
  float* wacc   = fr + 256;

  hipMemsetAsync(cnt, 0, cB, stream);
  hipMemsetAsync(wacc, 0, 2*sizeof(float), stream);

  conv_kernel<<<(N*64/8 + 255)/256, 256, 0, stream>>>(feat, featb, N*64/8);
  conv_kernel<<<(256*256/8 + 255)/256, 256, 0, stream>>>(fw1, fw1b, 256*256/8);
  conv_kernel<<<(128*256/8 + 255)/256, 256, 0, stream>>>(fw2, fw2b, 128*256/8);
  fr_kernel<<<1, 64, 0, stream>>>(rvec, fr);
  edge_kernel<<<dim3((E + 15)/16, 2), 256, 0, stream>>>(
      featb, inst, fr, attn1, attn2, eft, a_ws, cnt, bucket, E, N);
  seg_kernel<<<dim3((N + 3)/4, 2), 256, 0, stream>>>(a_ws, eft, cnt, bucket, z, E, N);
  mlp_kernel<<<(2*N + 63)/64, 256, 0, stream>>>(z, fw1b, fb1, fw2b, fb2, fw3, wacc, 2*N, N);
  beta_kernel<<<1, 64, 0, stream>>>(wacc, 1.f/(float)N);
  out_kernel<<<((N*256/8) + 255)/256, 256, 0, stream>>>(z, wacc, (float*)d_out, N*256);
}

// Round 4
// 431.252 us; speedup vs baseline: 1.8076x; 1.0493x over previous
//
#include <hip/hip_runtime.h>

typedef unsigned short u16;
typedef unsigned int   u32;
typedef short bf16x8 __attribute__((ext_vector_type(8)));
typedef float f32x4  __attribute__((ext_vector_type(4)));

#define CAP 64  // bucket capacity per segment (E/N = 5 avg; Poisson tail << 64)

__device__ inline float b2f(u16 u){ return __builtin_bit_cast(float, (u32)u << 16); }
__device__ inline u16 f2b(float f){
  u32 x = __builtin_bit_cast(u32, f);
  x += 0x7fffu + ((x >> 16) & 1u);   // RNE; values here are never NaN
  return (u16)(x >> 16);
}
__device__ inline void up2(u32 u, float& lo, float& hi){
  lo = __builtin_bit_cast(float, u << 16);
  hi = __builtin_bit_cast(float, u & 0xffff0000u);
}
__device__ inline float celu3(float x){
  return x > 0.f ? x : 3.f * expm1f(x * (1.f/3.f));
}
__device__ inline float sigm(float x){ return 1.f / (1.f + expf(-x)); }

// ---------------------------------------------------------------------------
// K0: fp32 -> bf16 pack, 8 elements/thread
// ---------------------------------------------------------------------------
__global__ __launch_bounds__(256) void conv_kernel(
    const float* __restrict__ src, u16* __restrict__ dst, int n8)
{
  int i = blockIdx.x * 256 + threadIdx.x;
  if (i >= n8) return;
  float4 a = ((const float4*)src)[2*i], b = ((const float4*)src)[2*i + 1];
  uint4 o;
  o.x = (u32)f2b(a.x) | ((u32)f2b(a.y) << 16);
  o.y = (u32)f2b(a.z) | ((u32)f2b(a.w) << 16);
  o.z = (u32)f2b(b.x) | ((u32)f2b(b.y) << 16);
  o.w = (u32)f2b(b.z) | ((u32)f2b(b.w) << 16);
  ((uint4*)dst)[i] = o;
}

// ---------------------------------------------------------------------------
// K1: rotor precompute (fp32). fr[m][p][c], p in {0,1}; p=2 identity (implicit)
// ---------------------------------------------------------------------------
__global__ void fr_kernel(const float* __restrict__ rvec, float* __restrict__ fr){
  int c = threadIdx.x;
  if (c >= 32) return;
  for (int m = 0; m < 2; ++m){
    float ar = rvec[(2*m)*64 + c*2],   ai = rvec[(2*m)*64 + c*2 + 1];
    float br = rvec[(2*m+1)*64 + c*2], bi = rvec[(2*m+1)*64 + c*2 + 1];
    float na = rsqrtf(ar*ar + ai*ai); ar *= na; ai *= na;
    float nb = rsqrtf(br*br + bi*bi); br *= nb; bi *= nb;
    float* f = fr + m*128;
    f[c*2]        = br*ar - bi*ai;   // p=0 (composed rotor)
    f[c*2 + 1]    = br*ai + bi*ar;
    f[64 + c*2]   = br;              // p=1
    f[64 + c*2+1] = bi;
  }
}

// ---------------------------------------------------------------------------
// K2: per-edge, 16 lanes/edge. Coalesced bf16 row gathers, full-line eft
// stores, shfl-reduced attention dots, bucket build.
// ---------------------------------------------------------------------------
__global__ __launch_bounds__(256) void edge_kernel(
    const u16* __restrict__ featb, const int* __restrict__ inst,
    const float* __restrict__ fr, const float* __restrict__ attn1,
    const float* __restrict__ attn2, u16* __restrict__ eft,
    float* __restrict__ a_ws, int* __restrict__ cnt, int* __restrict__ bucket,
    int E, int N)
{
  __shared__ float frs[128];
  __shared__ float w1s[256];
  __shared__ float w2s[256];
  int m = blockIdx.y;
  int t = threadIdx.x;
  if (t < 128) frs[t] = fr[m*128 + t];
  w1s[t] = attn1[t];
  w2s[t] = attn2[t];
  __syncthreads();

  int g = t >> 4, l = t & 15;           // group = edge, lane-in-group = 4 channels
  int e = blockIdx.x * 16 + g;
  if (e >= E) return;
  int base = (m*E + e)*3;
  int i0 = inst[base], i1 = inst[base+1], i2 = inst[base+2];

  const uint2* fb = (const uint2*)featb;             // 4 bf16 per uint2, 16/row
  uint2 v0 = fb[(size_t)i0*16 + l];
  uint2 v1 = fb[(size_t)i1*16 + l];
  uint2 v2 = fb[(size_t)i2*16 + l];
  float f0[4], f1[4], f2v[4];
  up2(v0.x, f0[0], f0[1]); up2(v0.y, f0[2], f0[3]);
  up2(v1.x, f1[0], f1[1]); up2(v1.y, f1[2], f1[3]);
  up2(v2.x, f2v[0], f2v[1]); up2(v2.y, f2v[2], f2v[3]);

  float4 R0 = *(const float4*)&frs[4*l];        // (Re c0, Im c0, Re c1, Im c1)
  float4 R1 = *(const float4*)&frs[64 + 4*l];

  float mre0 = (f0[0]*R0.x - f0[1]*R0.y + f1[0]*R1.x - f1[1]*R1.y + f2v[0]) * (1.f/3.f);
  float mim0 = (f0[0]*R0.y + f0[1]*R0.x + f1[0]*R1.y + f1[1]*R1.x + f2v[1]) * (1.f/3.f);
  float mre1 = (f0[2]*R0.z - f0[3]*R0.w + f1[2]*R1.z - f1[3]*R1.w + f2v[2]) * (1.f/3.f);
  float mim1 = (f0[2]*R0.w + f0[3]*R0.z + f1[2]*R1.w + f1[3]*R1.z + f2v[3]) * (1.f/3.f);

  float ef[4], s;
  s = celu3(mre0) * sigm(mre0); ef[0] = celu3(s);
  s = celu3(mim0) * sigm(mim0); ef[1] = celu3(s);
  s = celu3(mre1) * sigm(mre1); ef[2] = celu3(s);
  s = celu3(mim1) * sigm(mim1); ef[3] = celu3(s);

  ushort4 uo;
  uo.x = f2b(ef[0]); uo.y = f2b(ef[1]); uo.z = f2b(ef[2]); uo.w = f2b(ef[3]);
  ((ushort4*)eft)[(size_t)(m*E + e)*16 + l] = uo;   // wave: 4 edges x 128B contiguous

  float d1[4], d2[4];
  #pragma unroll
  for (int k = 0; k < 4; ++k){
    int wb = k*64 + l*4;
    d1[k] = f0[0]*w1s[wb] + f0[1]*w1s[wb+1] + f0[2]*w1s[wb+2] + f0[3]*w1s[wb+3];
    d2[k] = ef[0]*w2s[wb] + ef[1]*w2s[wb+1] + ef[2]*w2s[wb+2] + ef[3]*w2s[wb+3];
  }
  #pragma unroll
  for (int off = 8; off; off >>= 1){
    #pragma unroll
    for (int k = 0; k < 4; ++k){
      d1[k] += __shfl_xor(d1[k], off);
      d2[k] += __shfl_xor(d2[k], off);
    }
  }
  if (l == 0){
    float4 av;
    av.x = celu3(celu3(d1[0]) + d2[0]);
    av.y = celu3(celu3(d1[1]) + d2[1]);
    av.z = celu3(celu3(d1[2]) + d2[2]);
    av.w = celu3(celu3(d1[3]) + d2[3]);
    ((float4*)a_ws)[m*E + e] = av;
    int pos = atomicAdd(&cnt[m*N + i0], 1);
    if (pos < CAP) bucket[(size_t)(m*N + i0)*CAP + pos] = e;
  }
}

// ---------------------------------------------------------------------------
// K3: one wave per (segment, path): exact two-pass softmax over the bucket,
// z[n,k,h] = celu3(sum attn*eft) -> bf16
// ---------------------------------------------------------------------------
__global__ __launch_bounds__(256) void seg_kernel(
    const float* __restrict__ a_ws, const u16* __restrict__ eft,
    const int* __restrict__ cnt, const int* __restrict__ bucket,
    u16* __restrict__ z, int E, int N)
{
  int m = blockIdx.y;
  int n = blockIdx.x * 4 + (threadIdx.x >> 6);
  if (n >= N) return;
  int lane = threadIdx.x & 63;
  int sidx = m*N + n;
  int deg = cnt[sidx]; if (deg > CAP) deg = CAP;

  float h0=0.f, h1=0.f, h2=0.f, h3=0.f;
  if (deg > 0){
    const int* bk = bucket + (size_t)sidx * CAP;
    const float4* ap = (const float4*)a_ws;
    size_t ebase = (size_t)m * E;
    float m0=-1e30f, m1=-1e30f, m2=-1e30f, m3=-1e30f;
    for (int j = 0; j < deg; ++j){
      float4 av = ap[ebase + bk[j]];
      m0 = fmaxf(m0, av.x); m1 = fmaxf(m1, av.y);
      m2 = fmaxf(m2, av.z); m3 = fmaxf(m3, av.w);
    }
    float d0=0.f, d1=0.f, d2=0.f, d3=0.f;
    for (int j = 0; j < deg; ++j){
      int e = bk[j];
      float4 av = ap[ebase + e];
      float w0 = expf(av.x - m0), w1 = expf(av.y - m1);
      float w2 = expf(av.z - m2), w3 = expf(av.w - m3);
      d0 += w0; d1 += w1; d2 += w2; d3 += w3;
      float ev = b2f(eft[(ebase + e)*64 + lane]);
      h0 += w0*ev; h1 += w1*ev; h2 += w2*ev; h3 += w3*ev;
    }
    h0 /= d0; h1 /= d1; h2 /= d2; h3 /= d3;   // d >= 1 (max is in bucket)
  }
  u16* zr = z + (size_t)sidx*256 + lane;
  zr[0]   = f2b(celu3(h0));
  zr[64]  = f2b(celu3(h1));
  zr[128] = f2b(celu3(h2));
  zr[192] = f2b(celu3(h3));
}

// ---------------------------------------------------------------------------
// K4: fused 3-layer MLP (MFMA bf16), 64 rows/block.
// LDS: t2 tile overlays the z/t1 tile (barrier-separated) -> 34 KB, 4 blocks/CU.
// Weight B-fragments software-pipelined (next-ks prefetch in registers).
// ---------------------------------------------------------------------------
__global__ __launch_bounds__(256, 4) void mlp_kernel(
    const u16* __restrict__ z, const u16* __restrict__ fw1b, const float* __restrict__ fb1,
    const u16* __restrict__ fw2b, const float* __restrict__ fb2, const float* __restrict__ fw3,
    float* __restrict__ wacc, int rows, int N)
{
  __shared__ u16 buf[64][264];   // z tile -> t1 tile -> (overlaid) t2 tile
  __shared__ float fw3s[128];
  __shared__ float sArr[64];
  u16 (*t2t)[136] = (u16 (*)[136])&buf[0][0];
  int tid = threadIdx.x;
  int row0 = blockIdx.x * 64;

  if (tid < 128) fw3s[tid] = fw3[tid];

  // stage z (bf16 global) -> LDS; rows past `rows` zeroed
  const uint4* zg = (const uint4*)z;     // 8 bf16 per uint4, 32 per row
  #pragma unroll
  for (int it = 0; it < 8; ++it){
    int idx = it*256 + tid;
    int row = idx >> 5;
    int c8  = idx & 31;
    uint4 v = make_uint4(0u,0u,0u,0u);
    int gr = row0 + row;
    if (gr < rows) v = zg[(size_t)gr*32 + c8];
    *(uint4*)&buf[row][c8*8] = v;
  }
  __syncthreads();

  int wv = tid >> 6, lane = tid & 63, lr = lane & 15, quad = lane >> 4;
  f32x4 zero4 = {0.f, 0.f, 0.f, 0.f};

  // ---- layer 1: t1(64x256) = celu3(z @ fw1^T + fb1); wave wv owns cols [64wv,64wv+64)
  f32x4 acc[4][4];
  #pragma unroll
  for (int a = 0; a < 4; ++a)
    #pragma unroll
    for (int b = 0; b < 4; ++b) acc[a][b] = zero4;

  const u16* wb1 = fw1b + (size_t)(wv*64 + lr)*256 + quad*8;
  bf16x8 bfr[4], bnx[4];
  #pragma unroll
  for (int nt = 0; nt < 4; ++nt) bfr[nt] = *(const bf16x8*)(wb1 + nt*16*256);
  #pragma unroll
  for (int ks = 0; ks < 8; ++ks){
    if (ks < 7){
      #pragma unroll
      for (int nt = 0; nt < 4; ++nt)
        bnx[nt] = *(const bf16x8*)(wb1 + nt*16*256 + (ks+1)*32);
    }
    #pragma unroll
    for (int mt = 0; mt < 4; ++mt){
      bf16x8 af = *(const bf16x8*)&buf[mt*16 + lr][ks*32 + quad*8];
      #pragma unroll
      for (int nt = 0; nt < 4; ++nt)
        acc[mt][nt] = __builtin_amdgcn_mfma_f32_16x16x32_bf16(af, bfr[nt], acc[mt][nt], 0, 0, 0);
    }
    #pragma unroll
    for (int nt = 0; nt < 4; ++nt) bfr[nt] = bnx[nt];
  }
  __syncthreads();   // all z reads done before overwriting buf with t1
  #pragma unroll
  for (int nt = 0; nt < 4; ++nt){
    int col = wv*64 + nt*16 + lr;
    float bias = fb1[col];
    #pragma unroll
    for (int mt = 0; mt < 4; ++mt)
      #pragma unroll
      for (int ri = 0; ri < 4; ++ri){
        int row = mt*16 + quad*4 + ri;      // C/D: col=lane&15, row=(lane>>4)*4+reg
        buf[row][col] = f2b(celu3(acc[mt][nt][ri] + bias));
      }
  }
  __syncthreads();

  // ---- layer 2: t2(64x128) = celu3(t1 @ fw2^T + fb2); wave wv owns cols [32wv,32wv+32)
  f32x4 acc2[4][2];
  #pragma unroll
  for (int a = 0; a < 4; ++a){ acc2[a][0] = zero4; acc2[a][1] = zero4; }
  const u16* wb2 = fw2b + (size_t)(wv*32 + lr)*256 + quad*8;
  bf16x8 cfr[2], cnx[2];
  cfr[0] = *(const bf16x8*)(wb2);
  cfr[1] = *(const bf16x8*)(wb2 + 16*256);
  #pragma unroll
  for (int ks = 0; ks < 8; ++ks){
    if (ks < 7){
      cnx[0] = *(const bf16x8*)(wb2 + (ks+1)*32);
      cnx[1] = *(const bf16x8*)(wb2 + 16*256 + (ks+1)*32);
    }
    #pragma unroll
    for (int mt = 0; mt < 4; ++mt){
      bf16x8 af = *(const bf16x8*)&buf[mt*16 + lr][ks*32 + quad*8];
      acc2[mt][0] = __builtin_amdgcn_mfma_f32_16x16x32_bf16(af, cfr[0], acc2[mt][0], 0, 0, 0);
      acc2[mt][1] = __builtin_amdgcn_mfma_f32_16x16x32_bf16(af, cfr[1], acc2[mt][1], 0, 0, 0);
    }
    cfr[0] = cnx[0]; cfr[1] = cnx[1];
  }
  __syncthreads();   // all t1 reads done before overlaying buf with t2
  #pragma unroll
  for (int nt = 0; nt < 2; ++nt){
    int col = wv*32 + nt*16 + lr;
    float bias = fb2[col];
    #pragma unroll
    for (int mt = 0; mt < 4; ++mt)
      #pragma unroll
      for (int ri = 0; ri < 4; ++ri)
        t2t[mt*16 + quad*4 + ri][col] = f2b(celu3(acc2[mt][nt][ri] + bias));
  }
  __syncthreads();

  // ---- layer 3: s_r = t2[r,:] . fw3 ; 4 threads per row
  int r = tid >> 2, q = tid & 3;
  float p = 0.f;
  #pragma unroll
  for (int j = 0; j < 32; ++j){
    int jj = q*32 + j;
    p += b2f(t2t[r][jj]) * fw3s[jj];
  }
  p += __shfl_xor(p, 1);
  p += __shfl_xor(p, 2);
  if (q == 0) sArr[r] = p;
  __syncthreads();

  if (tid < 64){
    int gr = row0 + tid;
    float s  = (gr < rows) ? sArr[tid] : 0.f;
    float s0 = (gr < N) ? s : 0.f;      // path-0 rows are sidx < N
    float s1 = (gr < N) ? 0.f : s;
    #pragma unroll
    for (int off = 32; off; off >>= 1){
      s0 += __shfl_xor(s0, off);
      s1 += __shfl_xor(s1, off);
    }
    if (tid == 0){
      atomicAdd(&wacc[0], s0);
      atomicAdd(&wacc[1], s1);
    }
  }
}

// ---------------------------------------------------------------------------
// K5a: beta = softmax(w / N) over the 2 paths
// ---------------------------------------------------------------------------
__global__ void beta_kernel(float* __restrict__ wacc, float invN){
  if (threadIdx.x == 0 && blockIdx.x == 0){
    float w0 = wacc[0]*invN, w1 = wacc[1]*invN;
    float mx = fmaxf(w0, w1);
    float e0 = expf(w0 - mx), e1 = expf(w1 - mx);
    float s = e0 + e1;
    wacc[2] = e0 / s;
    wacc[3] = e1 / s;
  }
}

// ---------------------------------------------------------------------------
// K5b: out = beta0*z0 + beta1*z1 -> fp32
// ---------------------------------------------------------------------------
__global__ __launch_bounds__(256) void out_kernel(
    const u16* __restrict__ z, const float* __restrict__ wacc,
    float* __restrict__ out, int total)   // total = N*256
{
  int idx = blockIdx.x * 256 + threadIdx.x;   // one uint4 (8 bf16) per thread
  if (idx*8 >= total) return;
  float b0 = wacc[2], b1 = wacc[3];
  uint4 u0 = ((const uint4*)z)[idx];
  uint4 u1 = ((const uint4*)z)[(total >> 3) + idx];
  float a0,a1v,c0,c1;
  float4 o;
  up2(u0.x, a0, a1v); up2(u1.x, c0, c1);
  o.x = b0*a0 + b1*c0; o.y = b0*a1v + b1*c1;
  up2(u0.y, a0, a1v); up2(u1.y, c0, c1);
  o.z = b0*a0 + b1*c0; o.w = b0*a1v + b1*c1;
  ((float4*)out)[idx*2] = o;
  up2(u0.z, a0, a1v); up2(u1.z, c0, c1);
  o.x = b0*a0 + b1*c0; o.y = b0*a1v + b1*c1;
  up2(u0.w, a0, a1v); up2(u1.w, c0, c1);
  o.z = b0*a0 + b1*c0; o.w = b0*a1v + b1*c1;
  ((float4*)out)[idx*2 + 1] = o;
}

// ---------------------------------------------------------------------------
extern "C" void kernel_launch(void* const* d_in, const int* in_sizes, int n_in,
                              void* d_out, int out_size, void* d_ws, size_t ws_size,
                              hipStream_t stream)
{
  (void)n_in; (void)out_size; (void)ws_size;
  const float* feat  = (const float*)d_in[0];
  const float* rvec  = (const float*)d_in[1];
  const float* attn1 = (const float*)d_in[2];
  const float* attn2 = (const float*)d_in[3];
  const float* fw1   = (const float*)d_in[4];
  const float* fb1   = (const float*)d_in[5];
  const float* fw2   = (const float*)d_in[6];
  const float* fb2   = (const float*)d_in[7];
  const float* fw3   = (const float*)d_in[8];
  const int*   inst  = (const int*)d_in[9];

  int N = in_sizes[0] / 64;       // 50000
  int E = in_sizes[9] / 6;        // 250000

  char* ws = (char*)d_ws;
  u16*   z      = (u16*)ws;                            size_t zB = (size_t)2*N*256*2;
  u16*   eft    = (u16*)(ws + zB);                     size_t eB = (size_t)2*E*64*2;
  float* a_ws   = (float*)(ws + zB + eB);              size_t aB = (size_t)2*E*4*4;
  int*   bucket = (int*)(ws + zB + eB + aB);           size_t bB = (size_t)2*N*CAP*4;
  int*   cnt    = (int*)(ws + zB + eB + aB + bB);      size_t cB = (size_t)2*N*4;
  u16*   featb  = (u16*)(ws + zB + eB + aB + bB + cB); size_t fB = (size_t)N*64*2;
  u16*   fw1b   = (u16*)(ws + zB + eB + aB + bB + cB + fB);
  u16*   fw2b   = fw1b + 256*256;
  float* fr     = (float*)(fw2b + 128*256);
  float* wacc   = fr + 256;

  hipMemsetAsync(cnt, 0, cB, stream);
  hipMemsetAsync(wacc, 0, 2*sizeof(float), stream);

  conv_kernel<<<(N*64/8 + 255)/256, 256, 0, stream>>>(feat, featb, N*64/8);
  conv_kernel<<<(256*256/8 + 255)/256, 256, 0, stream>>>(fw1, fw1b, 256*256/8);
  conv_kernel<<<(128*256/8 + 255)/256, 256, 0, stream>>>(fw2, fw2b, 128*256/8);
  fr_kernel<<<1, 64, 0, stream>>>(rvec, fr);
  edge_kernel<<<dim3((E + 15)/16, 2), 256, 0, stream>>>(
      featb, inst, fr, attn1, attn2, eft, a_ws, cnt, bucket, E, N);
  seg_kernel<<<dim3((N + 3)/4, 2), 256, 0, stream>>>(a_ws, eft, cnt, bucket, z, E, N);
  mlp_kernel<<<(2*N + 63)/64, 256, 0, stream>>>(z, fw1b, fb1, fw2b, fb2, fw3, wacc, 2*N, N);
  beta_kernel<<<1, 64, 0, stream>>>(wacc, 1.f/(float)N);
  out_kernel<<<((N*256/8) + 255)/256, 256, 0, stream>>>(z, wacc, (float*)d_out, N*256);
}

// Round 5
// 331.010 us; speedup vs baseline: 2.3551x; 1.3028x over previous
//
#include <hip/hip_runtime.h>

typedef unsigned short u16;
typedef unsigned int   u32;
typedef short bf16x8 __attribute__((ext_vector_type(8)));
typedef float f32x4  __attribute__((ext_vector_type(4)));

#define CAP 64  // bucket capacity per segment == wave width (Poisson(5) tail @50k bins << 64)

__device__ inline float b2f(u16 u){ return __builtin_bit_cast(float, (u32)u << 16); }
__device__ inline u16 f2b(float f){
  u32 x = __builtin_bit_cast(u32, f);
  x += 0x7fffu + ((x >> 16) & 1u);   // RNE; values here are never NaN
  return (u16)(x >> 16);
}
__device__ inline void up2(u32 u, float& lo, float& hi){
  lo = __builtin_bit_cast(float, u << 16);
  hi = __builtin_bit_cast(float, u & 0xffff0000u);
}
// fast transcendentals: v_exp_f32-based; abs err ~1e-6, fine vs 0.036 threshold
__device__ inline float fexp(float x){ return __expf(x); }
__device__ inline float celu3(float x){
  return x > 0.f ? x : 3.f * (__expf(x * (1.f/3.f)) - 1.f);
}
__device__ inline float sigm(float x){ return 1.f / (1.f + __expf(-x)); }

// ---------------------------------------------------------------------------
// K0: fp32 -> bf16 pack, 8 elements/thread
// ---------------------------------------------------------------------------
__global__ __launch_bounds__(256) void conv_kernel(
    const float* __restrict__ src, u16* __restrict__ dst, int n8)
{
  int i = blockIdx.x * 256 + threadIdx.x;
  if (i >= n8) return;
  float4 a = ((const float4*)src)[2*i], b = ((const float4*)src)[2*i + 1];
  uint4 o;
  o.x = (u32)f2b(a.x) | ((u32)f2b(a.y) << 16);
  o.y = (u32)f2b(a.z) | ((u32)f2b(a.w) << 16);
  o.z = (u32)f2b(b.x) | ((u32)f2b(b.y) << 16);
  o.w = (u32)f2b(b.z) | ((u32)f2b(b.w) << 16);
  ((uint4*)dst)[i] = o;
}

// ---------------------------------------------------------------------------
// K1: rotor precompute (fp32). fr[m][p][c], p in {0,1}; p=2 identity (implicit)
// ---------------------------------------------------------------------------
__global__ void fr_kernel(const float* __restrict__ rvec, float* __restrict__ fr){
  int c = threadIdx.x;
  if (c >= 32) return;
  for (int m = 0; m < 2; ++m){
    float ar = rvec[(2*m)*64 + c*2],   ai = rvec[(2*m)*64 + c*2 + 1];
    float br = rvec[(2*m+1)*64 + c*2], bi = rvec[(2*m+1)*64 + c*2 + 1];
    float na = rsqrtf(ar*ar + ai*ai); ar *= na; ai *= na;
    float nb = rsqrtf(br*br + bi*bi); br *= nb; bi *= nb;
    float* f = fr + m*128;
    f[c*2]        = br*ar - bi*ai;   // p=0 (composed rotor)
    f[c*2 + 1]    = br*ai + bi*ar;
    f[64 + c*2]   = br;              // p=1
    f[64 + c*2+1] = bi;
  }
}

// ---------------------------------------------------------------------------
// K2: per-edge, 16 lanes/edge. Coalesced bf16 row gathers, full-line eft
// stores, shfl-reduced attention dots, bucket build.
// ---------------------------------------------------------------------------
__global__ __launch_bounds__(256) void edge_kernel(
    const u16* __restrict__ featb, const int* __restrict__ inst,
    const float* __restrict__ fr, const float* __restrict__ attn1,
    const float* __restrict__ attn2, u16* __restrict__ eft,
    float* __restrict__ a_ws, int* __restrict__ cnt, int* __restrict__ bucket,
    int E, int N)
{
  __shared__ float frs[128];
  __shared__ float w1s[256];
  __shared__ float w2s[256];
  int m = blockIdx.y;
  int t = threadIdx.x;
  if (t < 128) frs[t] = fr[m*128 + t];
  w1s[t] = attn1[t];
  w2s[t] = attn2[t];
  __syncthreads();

  int g = t >> 4, l = t & 15;           // group = edge, lane-in-group = 4 channels
  int e = blockIdx.x * 16 + g;
  if (e >= E) return;
  int base = (m*E + e)*3;
  int i0 = inst[base], i1 = inst[base+1], i2 = inst[base+2];

  const uint2* fb = (const uint2*)featb;             // 4 bf16 per uint2, 16/row
  uint2 v0 = fb[(size_t)i0*16 + l];
  uint2 v1 = fb[(size_t)i1*16 + l];
  uint2 v2 = fb[(size_t)i2*16 + l];
  float f0[4], f1[4], f2v[4];
  up2(v0.x, f0[0], f0[1]); up2(v0.y, f0[2], f0[3]);
  up2(v1.x, f1[0], f1[1]); up2(v1.y, f1[2], f1[3]);
  up2(v2.x, f2v[0], f2v[1]); up2(v2.y, f2v[2], f2v[3]);

  float4 R0 = *(const float4*)&frs[4*l];        // (Re c0, Im c0, Re c1, Im c1)
  float4 R1 = *(const float4*)&frs[64 + 4*l];

  float mre0 = (f0[0]*R0.x - f0[1]*R0.y + f1[0]*R1.x - f1[1]*R1.y + f2v[0]) * (1.f/3.f);
  float mim0 = (f0[0]*R0.y + f0[1]*R0.x + f1[0]*R1.y + f1[1]*R1.x + f2v[1]) * (1.f/3.f);
  float mre1 = (f0[2]*R0.z - f0[3]*R0.w + f1[2]*R1.z - f1[3]*R1.w + f2v[2]) * (1.f/3.f);
  float mim1 = (f0[2]*R0.w + f0[3]*R0.z + f1[2]*R1.w + f1[3]*R1.z + f2v[3]) * (1.f/3.f);

  float ef[4], s;
  s = celu3(mre0) * sigm(mre0); ef[0] = celu3(s);
  s = celu3(mim0) * sigm(mim0); ef[1] = celu3(s);
  s = celu3(mre1) * sigm(mre1); ef[2] = celu3(s);
  s = celu3(mim1) * sigm(mim1); ef[3] = celu3(s);

  ushort4 uo;
  uo.x = f2b(ef[0]); uo.y = f2b(ef[1]); uo.z = f2b(ef[2]); uo.w = f2b(ef[3]);
  ((ushort4*)eft)[(size_t)(m*E + e)*16 + l] = uo;   // wave: 4 edges x 128B contiguous

  float d1[4], d2[4];
  #pragma unroll
  for (int k = 0; k < 4; ++k){
    int wb = k*64 + l*4;
    d1[k] = f0[0]*w1s[wb] + f0[1]*w1s[wb+1] + f0[2]*w1s[wb+2] + f0[3]*w1s[wb+3];
    d2[k] = ef[0]*w2s[wb] + ef[1]*w2s[wb+1] + ef[2]*w2s[wb+2] + ef[3]*w2s[wb+3];
  }
  #pragma unroll
  for (int off = 8; off; off >>= 1){
    #pragma unroll
    for (int k = 0; k < 4; ++k){
      d1[k] += __shfl_xor(d1[k], off);
      d2[k] += __shfl_xor(d2[k], off);
    }
  }
  if (l == 0){
    float4 av;
    av.x = celu3(celu3(d1[0]) + d2[0]);
    av.y = celu3(celu3(d1[1]) + d2[1]);
    av.z = celu3(celu3(d1[2]) + d2[2]);
    av.w = celu3(celu3(d1[3]) + d2[3]);
    ((float4*)a_ws)[m*E + e] = av;
    int pos = atomicAdd(&cnt[m*N + i0], 1);
    if (pos < CAP) bucket[(size_t)(m*N + i0)*CAP + pos] = e;
  }
}

// ---------------------------------------------------------------------------
// K3: one wave per (segment, path), lane-parallel softmax: lane j owns edge j
// (deg <= 64). exp issued once per wave, not once per edge.
// ---------------------------------------------------------------------------
__global__ __launch_bounds__(256) void seg_kernel(
    const float* __restrict__ a_ws, const u16* __restrict__ eft,
    const int* __restrict__ cnt, const int* __restrict__ bucket,
    u16* __restrict__ z, int E, int N)
{
  int m = blockIdx.y;
  int n = blockIdx.x * 4 + (threadIdx.x >> 6);
  if (n >= N) return;
  int lane = threadIdx.x & 63;
  int sidx = m*N + n;
  int deg = cnt[sidx]; if (deg > CAP) deg = CAP;

  float h0=0.f, h1=0.f, h2=0.f, h3=0.f;
  if (deg > 0){
    const int* bk = bucket + (size_t)sidx * CAP;
    size_t ebase = (size_t)m * E;

    // lane j <- edge j
    int e = (lane < deg) ? bk[lane] : 0;
    float4 av = make_float4(-1e30f, -1e30f, -1e30f, -1e30f);
    if (lane < deg) av = ((const float4*)a_ws)[ebase + e];

    // wave max reduce (4 heads)
    float m0 = av.x, m1 = av.y, m2 = av.z, m3 = av.w;
    #pragma unroll
    for (int off = 32; off; off >>= 1){
      m0 = fmaxf(m0, __shfl_xor(m0, off));
      m1 = fmaxf(m1, __shfl_xor(m1, off));
      m2 = fmaxf(m2, __shfl_xor(m2, off));
      m3 = fmaxf(m3, __shfl_xor(m3, off));
    }
    // per-lane weights (single exp issue per head per wave)
    float w0 = 0.f, w1 = 0.f, w2 = 0.f, w3 = 0.f;
    if (lane < deg){
      w0 = fexp(av.x - m0); w1 = fexp(av.y - m1);
      w2 = fexp(av.z - m2); w3 = fexp(av.w - m3);
    }
    // wave sum reduce -> denominators
    float d0 = w0, d1 = w1, d2 = w2, d3 = w3;
    #pragma unroll
    for (int off = 32; off; off >>= 1){
      d0 += __shfl_xor(d0, off);
      d1 += __shfl_xor(d1, off);
      d2 += __shfl_xor(d2, off);
      d3 += __shfl_xor(d3, off);
    }
    w0 /= d0; w1 /= d1; w2 /= d2; w3 /= d3;

    // phase 2: weighted sum of eft rows (coalesced 128B row per iter)
    const u16* ep = eft + ebase*64;
    for (int j = 0; j < deg; ++j){
      int   ej  = __shfl(e,  j);
      float a0j = __shfl(w0, j), a1j = __shfl(w1, j);
      float a2j = __shfl(w2, j), a3j = __shfl(w3, j);
      float ev = b2f(ep[(size_t)ej*64 + lane]);
      h0 += a0j*ev; h1 += a1j*ev; h2 += a2j*ev; h3 += a3j*ev;
    }
  }
  u16* zr = z + (size_t)sidx*256 + lane;
  zr[0]   = f2b(celu3(h0));
  zr[64]  = f2b(celu3(h1));
  zr[128] = f2b(celu3(h2));
  zr[192] = f2b(celu3(h3));
}

// ---------------------------------------------------------------------------
// K4: fused 3-layer MLP (MFMA bf16), 64 rows/block.
// LDS: t2 tile overlays the z/t1 tile (barrier-separated) -> 34 KB, 4 blocks/CU.
// Weight B-fragments software-pipelined (next-ks prefetch in registers).
// ---------------------------------------------------------------------------
__global__ __launch_bounds__(256, 4) void mlp_kernel(
    const u16* __restrict__ z, const u16* __restrict__ fw1b, const float* __restrict__ fb1,
    const u16* __restrict__ fw2b, const float* __restrict__ fb2, const float* __restrict__ fw3,
    float* __restrict__ wacc, int rows, int N)
{
  __shared__ u16 buf[64][264];   // z tile -> t1 tile -> (overlaid) t2 tile
  __shared__ float fw3s[128];
  __shared__ float sArr[64];
  u16 (*t2t)[136] = (u16 (*)[136])&buf[0][0];
  int tid = threadIdx.x;
  int row0 = blockIdx.x * 64;

  if (tid < 128) fw3s[tid] = fw3[tid];

  // stage z (bf16 global) -> LDS; rows past `rows` zeroed
  const uint4* zg = (const uint4*)z;     // 8 bf16 per uint4, 32 per row
  #pragma unroll
  for (int it = 0; it < 8; ++it){
    int idx = it*256 + tid;
    int row = idx >> 5;
    int c8  = idx & 31;
    uint4 v = make_uint4(0u,0u,0u,0u);
    int gr = row0 + row;
    if (gr < rows) v = zg[(size_t)gr*32 + c8];
    *(uint4*)&buf[row][c8*8] = v;
  }
  __syncthreads();

  int wv = tid >> 6, lane = tid & 63, lr = lane & 15, quad = lane >> 4;
  f32x4 zero4 = {0.f, 0.f, 0.f, 0.f};

  // ---- layer 1: t1(64x256) = celu3(z @ fw1^T + fb1); wave wv owns cols [64wv,64wv+64)
  f32x4 acc[4][4];
  #pragma unroll
  for (int a = 0; a < 4; ++a)
    #pragma unroll
    for (int b = 0; b < 4; ++b) acc[a][b] = zero4;

  const u16* wb1 = fw1b + (size_t)(wv*64 + lr)*256 + quad*8;
  bf16x8 bfr[4], bnx[4];
  #pragma unroll
  for (int nt = 0; nt < 4; ++nt) bfr[nt] = *(const bf16x8*)(wb1 + nt*16*256);
  #pragma unroll
  for (int ks = 0; ks < 8; ++ks){
    if (ks < 7){
      #pragma unroll
      for (int nt = 0; nt < 4; ++nt)
        bnx[nt] = *(const bf16x8*)(wb1 + nt*16*256 + (ks+1)*32);
    }
    #pragma unroll
    for (int mt = 0; mt < 4; ++mt){
      bf16x8 af = *(const bf16x8*)&buf[mt*16 + lr][ks*32 + quad*8];
      #pragma unroll
      for (int nt = 0; nt < 4; ++nt)
        acc[mt][nt] = __builtin_amdgcn_mfma_f32_16x16x32_bf16(af, bfr[nt], acc[mt][nt], 0, 0, 0);
    }
    #pragma unroll
    for (int nt = 0; nt < 4; ++nt) bfr[nt] = bnx[nt];
  }
  __syncthreads();   // all z reads done before overwriting buf with t1
  #pragma unroll
  for (int nt = 0; nt < 4; ++nt){
    int col = wv*64 + nt*16 + lr;
    float bias = fb1[col];
    #pragma unroll
    for (int mt = 0; mt < 4; ++mt)
      #pragma unroll
      for (int ri = 0; ri < 4; ++ri){
        int row = mt*16 + quad*4 + ri;      // C/D: col=lane&15, row=(lane>>4)*4+reg
        buf[row][col] = f2b(celu3(acc[mt][nt][ri] + bias));
      }
  }
  __syncthreads();

  // ---- layer 2: t2(64x128) = celu3(t1 @ fw2^T + fb2); wave wv owns cols [32wv,32wv+32)
  f32x4 acc2[4][2];
  #pragma unroll
  for (int a = 0; a < 4; ++a){ acc2[a][0] = zero4; acc2[a][1] = zero4; }
  const u16* wb2 = fw2b + (size_t)(wv*32 + lr)*256 + quad*8;
  bf16x8 cfr[2], cnx[2];
  cfr[0] = *(const bf16x8*)(wb2);
  cfr[1] = *(const bf16x8*)(wb2 + 16*256);
  #pragma unroll
  for (int ks = 0; ks < 8; ++ks){
    if (ks < 7){
      cnx[0] = *(const bf16x8*)(wb2 + (ks+1)*32);
      cnx[1] = *(const bf16x8*)(wb2 + 16*256 + (ks+1)*32);
    }
    #pragma unroll
    for (int mt = 0; mt < 4; ++mt){
      bf16x8 af = *(const bf16x8*)&buf[mt*16 + lr][ks*32 + quad*8];
      acc2[mt][0] = __builtin_amdgcn_mfma_f32_16x16x32_bf16(af, cfr[0], acc2[mt][0], 0, 0, 0);
      acc2[mt][1] = __builtin_amdgcn_mfma_f32_16x16x32_bf16(af, cfr[1], acc2[mt][1], 0, 0, 0);
    }
    cfr[0] = cnx[0]; cfr[1] = cnx[1];
  }
  __syncthreads();   // all t1 reads done before overlaying buf with t2
  #pragma unroll
  for (int nt = 0; nt < 2; ++nt){
    int col = wv*32 + nt*16 + lr;
    float bias = fb2[col];
    #pragma unroll
    for (int mt = 0; mt < 4; ++mt)
      #pragma unroll
      for (int ri = 0; ri < 4; ++ri)
        t2t[mt*16 + quad*4 + ri][col] = f2b(celu3(acc2[mt][nt][ri] + bias));
  }
  __syncthreads();

  // ---- layer 3: s_r = t2[r,:] . fw3 ; 4 threads per row
  int r = tid >> 2, q = tid & 3;
  float p = 0.f;
  #pragma unroll
  for (int j = 0; j < 32; ++j){
    int jj = q*32 + j;
    p += b2f(t2t[r][jj]) * fw3s[jj];
  }
  p += __shfl_xor(p, 1);
  p += __shfl_xor(p, 2);
  if (q == 0) sArr[r] = p;
  __syncthreads();

  if (tid < 64){
    int gr = row0 + tid;
    float s  = (gr < rows) ? sArr[tid] : 0.f;
    float s0 = (gr < N) ? s : 0.f;      // path-0 rows are sidx < N
    float s1 = (gr < N) ? 0.f : s;
    #pragma unroll
    for (int off = 32; off; off >>= 1){
      s0 += __shfl_xor(s0, off);
      s1 += __shfl_xor(s1, off);
    }
    if (tid == 0){
      atomicAdd(&wacc[0], s0);
      atomicAdd(&wacc[1], s1);
    }
  }
}

// ---------------------------------------------------------------------------
// K5a: beta = softmax(w / N) over the 2 paths
// ---------------------------------------------------------------------------
__global__ void beta_kernel(float* __restrict__ wacc, float invN){
  if (threadIdx.x == 0 && blockIdx.x == 0){
    float w0 = wacc[0]*invN, w1 = wacc[1]*invN;
    float mx = fmaxf(w0, w1);
    float e0 = __expf(w0 - mx), e1 = __expf(w1 - mx);
    float s = e0 + e1;
    wacc[2] = e0 / s;
    wacc[3] = e1 / s;
  }
}

// ---------------------------------------------------------------------------
// K5b: out = beta0*z0 + beta1*z1 -> fp32
// ---------------------------------------------------------------------------
__global__ __launch_bounds__(256) void out_kernel(
    const u16* __restrict__ z, const float* __restrict__ wacc,
    float* __restrict__ out, int total)   // total = N*256
{
  int idx = blockIdx.x * 256 + threadIdx.x;   // one uint4 (8 bf16) per thread
  if (idx*8 >= total) return;
  float b0 = wacc[2], b1 = wacc[3];
  uint4 u0 = ((const uint4*)z)[idx];
  uint4 u1 = ((const uint4*)z)[(total >> 3) + idx];
  float a0,a1v,c0,c1;
  float4 o;
  up2(u0.x, a0, a1v); up2(u1.x, c0, c1);
  o.x = b0*a0 + b1*c0; o.y = b0*a1v + b1*c1;
  up2(u0.y, a0, a1v); up2(u1.y, c0, c1);
  o.z = b0*a0 + b1*c0; o.w = b0*a1v + b1*c1;
  ((float4*)out)[idx*2] = o;
  up2(u0.z, a0, a1v); up2(u1.z, c0, c1);
  o.x = b0*a0 + b1*c0; o.y = b0*a1v + b1*c1;
  up2(u0.w, a0, a1v); up2(u1.w, c0, c1);
  o.z = b0*a0 + b1*c0; o.w = b0*a1v + b1*c1;
  ((float4*)out)[idx*2 + 1] = o;
}

// ---------------------------------------------------------------------------
extern "C" void kernel_launch(void* const* d_in, const int* in_sizes, int n_in,
                              void* d_out, int out_size, void* d_ws, size_t ws_size,
                              hipStream_t stream)
{
  (void)n_in; (void)out_size; (void)ws_size;
  const float* feat  = (const float*)d_in[0];
  const float* rvec  = (const float*)d_in[1];
  const float* attn1 = (const float*)d_in[2];
  const float* attn2 = (const float*)d_in[3];
  const float* fw1   = (const float*)d_in[4];
  const float* fb1   = (const float*)d_in[5];
  const float* fw2   = (const float*)d_in[6];
  const float* fb2   = (const float*)d_in[7];
  const float* fw3   = (const float*)d_in[8];
  const int*   inst  = (const int*)d_in[9];

  int N = in_sizes[0] / 64;       // 50000
  int E = in_sizes[9] / 6;        // 250000

  char* ws = (char*)d_ws;
  u16*   z      = (u16*)ws;                            size_t zB = (size_t)2*N*256*2;
  u16*   eft    = (u16*)(ws + zB);                     size_t eB = (size_t)2*E*64*2;
  float* a_ws   = (float*)(ws + zB + eB);              size_t aB = (size_t)2*E*4*4;
  int*   bucket = (int*)(ws + zB + eB + aB);           size_t bB = (size_t)2*N*CAP*4;
  int*   cnt    = (int*)(ws + zB + eB + aB + bB);      size_t cB = (size_t)2*N*4;
  u16*   featb  = (u16*)(ws + zB + eB + aB + bB + cB); size_t fB = (size_t)N*64*2;
  u16*   fw1b   = (u16*)(ws + zB + eB + aB + bB + cB + fB);
  u16*   fw2b   = fw1b + 256*256;
  float* fr     = (float*)(fw2b + 128*256);
  float* wacc   = fr + 256;

  hipMemsetAsync(cnt, 0, cB, stream);
  hipMemsetAsync(wacc, 0, 2*sizeof(float), stream);

  conv_kernel<<<(N*64/8 + 255)/256, 256, 0, stream>>>(feat, featb, N*64/8);
  conv_kernel<<<(256*256/8 + 255)/256, 256, 0, stream>>>(fw1, fw1b, 256*256/8);
  conv_kernel<<<(128*256/8 + 255)/256, 256, 0, stream>>>(fw2, fw2b, 128*256/8);
  fr_kernel<<<1, 64, 0, stream>>>(rvec, fr);
  edge_kernel<<<dim3((E + 15)/16, 2), 256, 0, stream>>>(
      featb, inst, fr, attn1, attn2, eft, a_ws, cnt, bucket, E, N);
  seg_kernel<<<dim3((N + 3)/4, 2), 256, 0, stream>>>(a_ws, eft, cnt, bucket, z, E, N);
  mlp_kernel<<<(2*N + 63)/64, 256, 0, stream>>>(z, fw1b, fb1, fw2b, fb2, fw3, wacc, 2*N, N);
  beta_kernel<<<1, 64, 0, stream>>>(wacc, 1.f/(float)N);
  out_kernel<<<((N*256/8) + 255)/256, 256, 0, stream>>>(z, wacc, (float*)d_out, N*256);
}

// Round 6
// 310.258 us; speedup vs baseline: 2.5126x; 1.0669x over previous
//
#include <hip/hip_runtime.h>

typedef unsigned short u16;
typedef unsigned int   u32;
typedef short bf16x8 __attribute__((ext_vector_type(8)));
typedef float f32x4  __attribute__((ext_vector_type(4)));

#define CAP 64  // bucket capacity per segment == wave width (max degree ~16 for this dataset)

__device__ inline float b2f(u16 u){ return __builtin_bit_cast(float, (u32)u << 16); }
__device__ inline u16 f2b(float f){
  u32 x = __builtin_bit_cast(u32, f);
  x += 0x7fffu + ((x >> 16) & 1u);   // RNE; values here are never NaN
  return (u16)(x >> 16);
}
__device__ inline void up2(u32 u, float& lo, float& hi){
  lo = __builtin_bit_cast(float, u << 16);
  hi = __builtin_bit_cast(float, u & 0xffff0000u);
}
// fast transcendentals: v_exp_f32-based; abs err ~1e-6, fine vs 0.036 threshold
__device__ inline float fexp(float x){ return __expf(x); }
__device__ inline float celu3(float x){
  return x > 0.f ? x : 3.f * (__expf(x * (1.f/3.f)) - 1.f);
}
__device__ inline float sigm(float x){ return 1.f / (1.f + __expf(-x)); }

// ---------------------------------------------------------------------------
// K0: fp32 -> bf16 pack, 8 elements/thread
// ---------------------------------------------------------------------------
__global__ __launch_bounds__(256) void conv_kernel(
    const float* __restrict__ src, u16* __restrict__ dst, int n8)
{
  int i = blockIdx.x * 256 + threadIdx.x;
  if (i >= n8) return;
  float4 a = ((const float4*)src)[2*i], b = ((const float4*)src)[2*i + 1];
  uint4 o;
  o.x = (u32)f2b(a.x) | ((u32)f2b(a.y) << 16);
  o.y = (u32)f2b(a.z) | ((u32)f2b(a.w) << 16);
  o.z = (u32)f2b(b.x) | ((u32)f2b(b.y) << 16);
  o.w = (u32)f2b(b.z) | ((u32)f2b(b.w) << 16);
  ((uint4*)dst)[i] = o;
}

// ---------------------------------------------------------------------------
// K1: rotor precompute (fp32). fr[m][p][c], p in {0,1}; p=2 identity (implicit)
// ---------------------------------------------------------------------------
__global__ void fr_kernel(const float* __restrict__ rvec, float* __restrict__ fr){
  int c = threadIdx.x;
  if (c >= 32) return;
  for (int m = 0; m < 2; ++m){
    float ar = rvec[(2*m)*64 + c*2],   ai = rvec[(2*m)*64 + c*2 + 1];
    float br = rvec[(2*m+1)*64 + c*2], bi = rvec[(2*m+1)*64 + c*2 + 1];
    float na = rsqrtf(ar*ar + ai*ai); ar *= na; ai *= na;
    float nb = rsqrtf(br*br + bi*bi); br *= nb; bi *= nb;
    float* f = fr + m*128;
    f[c*2]        = br*ar - bi*ai;   // p=0 (composed rotor)
    f[c*2 + 1]    = br*ai + bi*ar;
    f[64 + c*2]   = br;              // p=1
    f[64 + c*2+1] = bi;
  }
}

// ---------------------------------------------------------------------------
// K2: per-edge, 16 lanes/edge. Coalesced bf16 row gathers, full-line eft
// stores, shfl-reduced attention dots, bucket build.
// ---------------------------------------------------------------------------
__global__ __launch_bounds__(256) void edge_kernel(
    const u16* __restrict__ featb, const int* __restrict__ inst,
    const float* __restrict__ fr, const float* __restrict__ attn1,
    const float* __restrict__ attn2, u16* __restrict__ eft,
    float* __restrict__ a_ws, int* __restrict__ cnt, int* __restrict__ bucket,
    int E, int N)
{
  __shared__ float frs[128];
  __shared__ float w1s[256];
  __shared__ float w2s[256];
  int m = blockIdx.y;
  int t = threadIdx.x;
  if (t < 128) frs[t] = fr[m*128 + t];
  w1s[t] = attn1[t];
  w2s[t] = attn2[t];
  __syncthreads();

  int g = t >> 4, l = t & 15;           // group = edge, lane-in-group = 4 channels
  int e = blockIdx.x * 16 + g;
  if (e >= E) return;
  int base = (m*E + e)*3;
  int i0 = inst[base], i1 = inst[base+1], i2 = inst[base+2];

  const uint2* fb = (const uint2*)featb;             // 4 bf16 per uint2, 16/row
  uint2 v0 = fb[(size_t)i0*16 + l];
  uint2 v1 = fb[(size_t)i1*16 + l];
  uint2 v2 = fb[(size_t)i2*16 + l];
  float f0[4], f1[4], f2v[4];
  up2(v0.x, f0[0], f0[1]); up2(v0.y, f0[2], f0[3]);
  up2(v1.x, f1[0], f1[1]); up2(v1.y, f1[2], f1[3]);
  up2(v2.x, f2v[0], f2v[1]); up2(v2.y, f2v[2], f2v[3]);

  float4 R0 = *(const float4*)&frs[4*l];        // (Re c0, Im c0, Re c1, Im c1)
  float4 R1 = *(const float4*)&frs[64 + 4*l];

  float mre0 = (f0[0]*R0.x - f0[1]*R0.y + f1[0]*R1.x - f1[1]*R1.y + f2v[0]) * (1.f/3.f);
  float mim0 = (f0[0]*R0.y + f0[1]*R0.x + f1[0]*R1.y + f1[1]*R1.x + f2v[1]) * (1.f/3.f);
  float mre1 = (f0[2]*R0.z - f0[3]*R0.w + f1[2]*R1.z - f1[3]*R1.w + f2v[2]) * (1.f/3.f);
  float mim1 = (f0[2]*R0.w + f0[3]*R0.z + f1[2]*R1.w + f1[3]*R1.z + f2v[3]) * (1.f/3.f);

  float ef[4], s;
  s = celu3(mre0) * sigm(mre0); ef[0] = celu3(s);
  s = celu3(mim0) * sigm(mim0); ef[1] = celu3(s);
  s = celu3(mre1) * sigm(mre1); ef[2] = celu3(s);
  s = celu3(mim1) * sigm(mim1); ef[3] = celu3(s);

  ushort4 uo;
  uo.x = f2b(ef[0]); uo.y = f2b(ef[1]); uo.z = f2b(ef[2]); uo.w = f2b(ef[3]);
  ((ushort4*)eft)[(size_t)(m*E + e)*16 + l] = uo;   // wave: 4 edges x 128B contiguous

  float d1[4], d2[4];
  #pragma unroll
  for (int k = 0; k < 4; ++k){
    int wb = k*64 + l*4;
    d1[k] = f0[0]*w1s[wb] + f0[1]*w1s[wb+1] + f0[2]*w1s[wb+2] + f0[3]*w1s[wb+3];
    d2[k] = ef[0]*w2s[wb] + ef[1]*w2s[wb+1] + ef[2]*w2s[wb+2] + ef[3]*w2s[wb+3];
  }
  #pragma unroll
  for (int off = 8; off; off >>= 1){
    #pragma unroll
    for (int k = 0; k < 4; ++k){
      d1[k] += __shfl_xor(d1[k], off);
      d2[k] += __shfl_xor(d2[k], off);
    }
  }
  if (l == 0){
    float4 av;
    av.x = celu3(celu3(d1[0]) + d2[0]);
    av.y = celu3(celu3(d1[1]) + d2[1]);
    av.z = celu3(celu3(d1[2]) + d2[2]);
    av.w = celu3(celu3(d1[3]) + d2[3]);
    ((float4*)a_ws)[m*E + e] = av;
    int pos = atomicAdd(&cnt[m*N + i0], 1);
    if (pos < CAP) bucket[(size_t)(m*N + i0)*CAP + pos] = e;
  }
}

// ---------------------------------------------------------------------------
// K3: one wave per (segment, path), lane-parallel softmax WITHOUT reduction
// trees: exp(a) is safe un-shifted (|a| <= ~7 by construction), and the
// denominator is accumulated from the already-broadcast weights in phase 2.
// softmax(a) == softmax(a - amax) exactly (ratio identity).
// ---------------------------------------------------------------------------
__global__ __launch_bounds__(256) void seg_kernel(
    const float* __restrict__ a_ws, const u16* __restrict__ eft,
    const int* __restrict__ cnt, const int* __restrict__ bucket,
    u16* __restrict__ z, int E, int N)
{
  int m = blockIdx.y;
  int n = blockIdx.x * 4 + (threadIdx.x >> 6);
  if (n >= N) return;
  int lane = threadIdx.x & 63;
  int sidx = m*N + n;
  int deg = cnt[sidx]; if (deg > CAP) deg = CAP;

  float h0=0.f, h1=0.f, h2=0.f, h3=0.f;
  float d0=0.f, d1=0.f, d2=0.f, d3=0.f;
  if (deg > 0){
    const int* bk = bucket + (size_t)sidx * CAP;
    size_t ebase = (size_t)m * E;

    // lane j <- edge j: coalesced bucket read + 16B a gather + one exp
    int e = (lane < deg) ? bk[lane] : 0;
    float w0 = 0.f, w1 = 0.f, w2 = 0.f, w3 = 0.f;
    if (lane < deg){
      float4 av = ((const float4*)a_ws)[ebase + e];
      w0 = fexp(av.x); w1 = fexp(av.y); w2 = fexp(av.z); w3 = fexp(av.w);
    }

    // phase 2: weighted sum of eft rows (coalesced 128B row per iter);
    // denominators accumulate from the broadcast weights (no shfl tree).
    const u16* ep = eft + ebase*64;
    for (int j = 0; j < deg; ++j){
      int   ej  = __shfl(e,  j);
      float a0j = __shfl(w0, j), a1j = __shfl(w1, j);
      float a2j = __shfl(w2, j), a3j = __shfl(w3, j);
      float ev = b2f(ep[(size_t)ej*64 + lane]);
      h0 += a0j*ev; h1 += a1j*ev; h2 += a2j*ev; h3 += a3j*ev;
      d0 += a0j;    d1 += a1j;    d2 += a2j;    d3 += a3j;
    }
    h0 /= d0; h1 /= d1; h2 /= d2; h3 /= d3;
  }
  u16* zr = z + (size_t)sidx*256 + lane;
  zr[0]   = f2b(celu3(h0));
  zr[64]  = f2b(celu3(h1));
  zr[128] = f2b(celu3(h2));
  zr[192] = f2b(celu3(h3));
}

// ---------------------------------------------------------------------------
// K4: fused 3-layer MLP (MFMA bf16), 64 rows/block.
// LDS: t2 tile overlays the z/t1 tile (barrier-separated) -> 34 KB, 4 blocks/CU.
// Weight B-fragments software-pipelined (next-ks prefetch in registers).
// ---------------------------------------------------------------------------
__global__ __launch_bounds__(256, 4) void mlp_kernel(
    const u16* __restrict__ z, const u16* __restrict__ fw1b, const float* __restrict__ fb1,
    const u16* __restrict__ fw2b, const float* __restrict__ fb2, const float* __restrict__ fw3,
    float* __restrict__ wacc, int rows, int N)
{
  __shared__ u16 buf[64][264];   // z tile -> t1 tile -> (overlaid) t2 tile
  __shared__ float fw3s[128];
  __shared__ float sArr[64];
  u16 (*t2t)[136] = (u16 (*)[136])&buf[0][0];
  int tid = threadIdx.x;
  int row0 = blockIdx.x * 64;

  if (tid < 128) fw3s[tid] = fw3[tid];

  // stage z (bf16 global) -> LDS; rows past `rows` zeroed
  const uint4* zg = (const uint4*)z;     // 8 bf16 per uint4, 32 per row
  #pragma unroll
  for (int it = 0; it < 8; ++it){
    int idx = it*256 + tid;
    int row = idx >> 5;
    int c8  = idx & 31;
    uint4 v = make_uint4(0u,0u,0u,0u);
    int gr = row0 + row;
    if (gr < rows) v = zg[(size_t)gr*32 + c8];
    *(uint4*)&buf[row][c8*8] = v;
  }
  __syncthreads();

  int wv = tid >> 6, lane = tid & 63, lr = lane & 15, quad = lane >> 4;
  f32x4 zero4 = {0.f, 0.f, 0.f, 0.f};

  // ---- layer 1: t1(64x256) = celu3(z @ fw1^T + fb1); wave wv owns cols [64wv,64wv+64)
  f32x4 acc[4][4];
  #pragma unroll
  for (int a = 0; a < 4; ++a)
    #pragma unroll
    for (int b = 0; b < 4; ++b) acc[a][b] = zero4;

  const u16* wb1 = fw1b + (size_t)(wv*64 + lr)*256 + quad*8;
  bf16x8 bfr[4], bnx[4];
  #pragma unroll
  for (int nt = 0; nt < 4; ++nt) bfr[nt] = *(const bf16x8*)(wb1 + nt*16*256);
  #pragma unroll
  for (int ks = 0; ks < 8; ++ks){
    if (ks < 7){
      #pragma unroll
      for (int nt = 0; nt < 4; ++nt)
        bnx[nt] = *(const bf16x8*)(wb1 + nt*16*256 + (ks+1)*32);
    }
    #pragma unroll
    for (int mt = 0; mt < 4; ++mt){
      bf16x8 af = *(const bf16x8*)&buf[mt*16 + lr][ks*32 + quad*8];
      #pragma unroll
      for (int nt = 0; nt < 4; ++nt)
        acc[mt][nt] = __builtin_amdgcn_mfma_f32_16x16x32_bf16(af, bfr[nt], acc[mt][nt], 0, 0, 0);
    }
    #pragma unroll
    for (int nt = 0; nt < 4; ++nt) bfr[nt] = bnx[nt];
  }
  __syncthreads();   // all z reads done before overwriting buf with t1
  #pragma unroll
  for (int nt = 0; nt < 4; ++nt){
    int col = wv*64 + nt*16 + lr;
    float bias = fb1[col];
    #pragma unroll
    for (int mt = 0; mt < 4; ++mt)
      #pragma unroll
      for (int ri = 0; ri < 4; ++ri){
        int row = mt*16 + quad*4 + ri;      // C/D: col=lane&15, row=(lane>>4)*4+reg
        buf[row][col] = f2b(celu3(acc[mt][nt][ri] + bias));
      }
  }
  __syncthreads();

  // ---- layer 2: t2(64x128) = celu3(t1 @ fw2^T + fb2); wave wv owns cols [32wv,32wv+32)
  f32x4 acc2[4][2];
  #pragma unroll
  for (int a = 0; a < 4; ++a){ acc2[a][0] = zero4; acc2[a][1] = zero4; }
  const u16* wb2 = fw2b + (size_t)(wv*32 + lr)*256 + quad*8;
  bf16x8 cfr[2], cnx[2];
  cfr[0] = *(const bf16x8*)(wb2);
  cfr[1] = *(const bf16x8*)(wb2 + 16*256);
  #pragma unroll
  for (int ks = 0; ks < 8; ++ks){
    if (ks < 7){
      cnx[0] = *(const bf16x8*)(wb2 + (ks+1)*32);
      cnx[1] = *(const bf16x8*)(wb2 + 16*256 + (ks+1)*32);
    }
    #pragma unroll
    for (int mt = 0; mt < 4; ++mt){
      bf16x8 af = *(const bf16x8*)&buf[mt*16 + lr][ks*32 + quad*8];
      acc2[mt][0] = __builtin_amdgcn_mfma_f32_16x16x32_bf16(af, cfr[0], acc2[mt][0], 0, 0, 0);
      acc2[mt][1] = __builtin_amdgcn_mfma_f32_16x16x32_bf16(af, cfr[1], acc2[mt][1], 0, 0, 0);
    }
    cfr[0] = cnx[0]; cfr[1] = cnx[1];
  }
  __syncthreads();   // all t1 reads done before overlaying buf with t2
  #pragma unroll
  for (int nt = 0; nt < 2; ++nt){
    int col = wv*32 + nt*16 + lr;
    float bias = fb2[col];
    #pragma unroll
    for (int mt = 0; mt < 4; ++mt)
      #pragma unroll
      for (int ri = 0; ri < 4; ++ri)
        t2t[mt*16 + quad*4 + ri][col] = f2b(celu3(acc2[mt][nt][ri] + bias));
  }
  __syncthreads();

  // ---- layer 3: s_r = t2[r,:] . fw3 ; 4 threads per row
  int r = tid >> 2, q = tid & 3;
  float p = 0.f;
  #pragma unroll
  for (int j = 0; j < 32; ++j){
    int jj = q*32 + j;
    p += b2f(t2t[r][jj]) * fw3s[jj];
  }
  p += __shfl_xor(p, 1);
  p += __shfl_xor(p, 2);
  if (q == 0) sArr[r] = p;
  __syncthreads();

  if (tid < 64){
    int gr = row0 + tid;
    float s  = (gr < rows) ? sArr[tid] : 0.f;
    float s0 = (gr < N) ? s : 0.f;      // path-0 rows are sidx < N
    float s1 = (gr < N) ? 0.f : s;
    #pragma unroll
    for (int off = 32; off; off >>= 1){
      s0 += __shfl_xor(s0, off);
      s1 += __shfl_xor(s1, off);
    }
    if (tid == 0){
      atomicAdd(&wacc[0], s0);
      atomicAdd(&wacc[1], s1);
    }
  }
}

// ---------------------------------------------------------------------------
// K5a: beta = softmax(w / N) over the 2 paths
// ---------------------------------------------------------------------------
__global__ void beta_kernel(float* __restrict__ wacc, float invN){
  if (threadIdx.x == 0 && blockIdx.x == 0){
    float w0 = wacc[0]*invN, w1 = wacc[1]*invN;
    float mx = fmaxf(w0, w1);
    float e0 = __expf(w0 - mx), e1 = __expf(w1 - mx);
    float s = e0 + e1;
    wacc[2] = e0 / s;
    wacc[3] = e1 / s;
  }
}

// ---------------------------------------------------------------------------
// K5b: out = beta0*z0 + beta1*z1 -> fp32
// ---------------------------------------------------------------------------
__global__ __launch_bounds__(256) void out_kernel(
    const u16* __restrict__ z, const float* __restrict__ wacc,
    float* __restrict__ out, int total)   // total = N*256
{
  int idx = blockIdx.x * 256 + threadIdx.x;   // one uint4 (8 bf16) per thread
  if (idx*8 >= total) return;
  float b0 = wacc[2], b1 = wacc[3];
  uint4 u0 = ((const uint4*)z)[idx];
  uint4 u1 = ((const uint4*)z)[(total >> 3) + idx];
  float a0,a1v,c0,c1;
  float4 o;
  up2(u0.x, a0, a1v); up2(u1.x, c0, c1);
  o.x = b0*a0 + b1*c0; o.y = b0*a1v + b1*c1;
  up2(u0.y, a0, a1v); up2(u1.y, c0, c1);
  o.z = b0*a0 + b1*c0; o.w = b0*a1v + b1*c1;
  ((float4*)out)[idx*2] = o;
  up2(u0.z, a0, a1v); up2(u1.z, c0, c1);
  o.x = b0*a0 + b1*c0; o.y = b0*a1v + b1*c1;
  up2(u0.w, a0, a1v); up2(u1.w, c0, c1);
  o.z = b0*a0 + b1*c0; o.w = b0*a1v + b1*c1;
  ((float4*)out)[idx*2 + 1] = o;
}

// ---------------------------------------------------------------------------
extern "C" void kernel_launch(void* const* d_in, const int* in_sizes, int n_in,
                              void* d_out, int out_size, void* d_ws, size_t ws_size,
                              hipStream_t stream)
{
  (void)n_in; (void)out_size; (void)ws_size;
  const float* feat  = (const float*)d_in[0];
  const float* rvec  = (const float*)d_in[1];
  const float* attn1 = (const float*)d_in[2];
  const float* attn2 = (const float*)d_in[3];
  const float* fw1   = (const float*)d_in[4];
  const float* fb1   = (const float*)d_in[5];
  const float* fw2   = (const float*)d_in[6];
  const float* fb2   = (const float*)d_in[7];
  const float* fw3   = (const float*)d_in[8];
  const int*   inst  = (const int*)d_in[9];

  int N = in_sizes[0] / 64;       // 50000
  int E = in_sizes[9] / 6;        // 250000

  char* ws = (char*)d_ws;
  u16*   z      = (u16*)ws;                            size_t zB = (size_t)2*N*256*2;
  u16*   eft    = (u16*)(ws + zB);                     size_t eB = (size_t)2*E*64*2;
  float* a_ws   = (float*)(ws + zB + eB);              size_t aB = (size_t)2*E*4*4;
  int*   bucket = (int*)(ws + zB + eB + aB);           size_t bB = (size_t)2*N*CAP*4;
  int*   cnt    = (int*)(ws + zB + eB + aB + bB);      size_t cB = (size_t)2*N*4;
  u16*   featb  = (u16*)(ws + zB + eB + aB + bB + cB); size_t fB = (size_t)N*64*2;
  u16*   fw1b   = (u16*)(ws + zB + eB + aB + bB + cB + fB);
  u16*   fw2b   = fw1b + 256*256;
  float* fr     = (float*)(fw2b + 128*256);
  float* wacc   = fr + 256;

  hipMemsetAsync(cnt, 0, cB, stream);
  hipMemsetAsync(wacc, 0, 2*sizeof(float), stream);

  conv_kernel<<<(N*64/8 + 255)/256, 256, 0, stream>>>(feat, featb, N*64/8);
  conv_kernel<<<(256*256/8 + 255)/256, 256, 0, stream>>>(fw1, fw1b, 256*256/8);
  conv_kernel<<<(128*256/8 + 255)/256, 256, 0, stream>>>(fw2, fw2b, 128*256/8);
  fr_kernel<<<1, 64, 0, stream>>>(rvec, fr);
  edge_kernel<<<dim3((E + 15)/16, 2), 256, 0, stream>>>(
      featb, inst, fr, attn1, attn2, eft, a_ws, cnt, bucket, E, N);
  seg_kernel<<<dim3((N + 3)/4, 2), 256, 0, stream>>>(a_ws, eft, cnt, bucket, z, E, N);
  mlp_kernel<<<(2*N + 63)/64, 256, 0, stream>>>(z, fw1b, fb1, fw2b, fb2, fw3, wacc, 2*N, N);
  beta_kernel<<<1, 64, 0, stream>>>(wacc, 1.f/(float)N);
  out_kernel<<<((N*256/8) + 255)/256, 256, 0, stream>>>(z, wacc, (float*)d_out, N*256);
}

// Round 8
// 302.724 us; speedup vs baseline: 2.5751x; 1.0249x over previous
//
#include <hip/hip_runtime.h>
#include <hip/hip_bf16.h>

typedef unsigned short u16;
typedef unsigned int   u32;
typedef short bf16x8 __attribute__((ext_vector_type(8)));
typedef float f32x4  __attribute__((ext_vector_type(4)));

#define CAP 64  // bucket capacity per segment == wave width (max degree ~16 for this dataset)

__device__ inline float b2f(u16 u){ return __builtin_bit_cast(float, (u32)u << 16); }
__device__ inline u16 f2b(float f){
  u32 x = __builtin_bit_cast(u32, f);
  x += 0x7fffu + ((x >> 16) & 1u);   // RNE; values here are never NaN
  return (u16)(x >> 16);
}
// packed RNE cvt: 2 floats -> 1 u32 (v_cvt_pk_bf16_f32 on gfx950)
__device__ inline u32 pk2(float lo, float hi){
  float2 f; f.x = lo; f.y = hi;
  __hip_bfloat162 h = __float22bfloat162_rn(f);
  u32 r; __builtin_memcpy(&r, &h, 4);   // bit_cast rejected: non-trivial copy ctor
  return r;
}
__device__ inline void up2(u32 u, float& lo, float& hi){
  lo = __builtin_bit_cast(float, u << 16);
  hi = __builtin_bit_cast(float, u & 0xffff0000u);
}
// fast transcendentals: v_exp_f32-based; abs err ~1e-6, fine vs 0.036 threshold
__device__ inline float fexp(float x){ return __expf(x); }
__device__ inline float celu3(float x){
  return x > 0.f ? x : 3.f * (__expf(x * (1.f/3.f)) - 1.f);
}
__device__ inline float sigm(float x){ return 1.f / (1.f + __expf(-x)); }

// ---------------------------------------------------------------------------
// K0: fp32 -> bf16 pack, 8 elements/thread (weights only)
// ---------------------------------------------------------------------------
__global__ __launch_bounds__(256) void conv_kernel(
    const float* __restrict__ src, u16* __restrict__ dst, int n8)
{
  int i = blockIdx.x * 256 + threadIdx.x;
  if (i >= n8) return;
  float4 a = ((const float4*)src)[2*i], b = ((const float4*)src)[2*i + 1];
  uint4 o;
  o.x = pk2(a.x, a.y);
  o.y = pk2(a.z, a.w);
  o.z = pk2(b.x, b.y);
  o.w = pk2(b.z, b.w);
  ((uint4*)dst)[i] = o;
}

// ---------------------------------------------------------------------------
// K0b: per-node precompute, 16 lanes/node:
//   featb[n] = bf16(feat[n])            (absorbs the old feature conv pass)
//   a1c[n]   = celu3(feat[n] @ attn1^T) (was recomputed 10x per edge-path)
// ---------------------------------------------------------------------------
__global__ __launch_bounds__(256) void a1_kernel(
    const float* __restrict__ feat, const float* __restrict__ attn1,
    u16* __restrict__ featb, float* __restrict__ a1c, int N)
{
  __shared__ float w1s[256];
  int t = threadIdx.x;
  w1s[t] = attn1[t];
  __syncthreads();
  int g = t >> 4, l = t & 15;
  int n = blockIdx.x * 16 + g;
  if (n >= N) return;
  float4 x = ((const float4*)feat)[(size_t)n*16 + l];   // channels 4l..4l+3
  uint2 o;
  o.x = pk2(x.x, x.y);
  o.y = pk2(x.z, x.w);
  ((uint2*)featb)[(size_t)n*16 + l] = o;
  float d[4];
  #pragma unroll
  for (int k = 0; k < 4; ++k){
    int wb = k*64 + l*4;
    d[k] = x.x*w1s[wb] + x.y*w1s[wb+1] + x.z*w1s[wb+2] + x.w*w1s[wb+3];
  }
  #pragma unroll
  for (int off = 8; off; off >>= 1){
    #pragma unroll
    for (int k = 0; k < 4; ++k) d[k] += __shfl_xor(d[k], off);
  }
  if (l == 0){
    float4 av;
    av.x = celu3(d[0]); av.y = celu3(d[1]);
    av.z = celu3(d[2]); av.w = celu3(d[3]);
    ((float4*)a1c)[n] = av;
  }
}

// ---------------------------------------------------------------------------
// K1: rotor precompute (fp32). fr[m][p][c], p in {0,1}; p=2 identity (implicit)
// ---------------------------------------------------------------------------
__global__ void fr_kernel(const float* __restrict__ rvec, float* __restrict__ fr){
  int c = threadIdx.x;
  if (c >= 32) return;
  for (int m = 0; m < 2; ++m){
    float ar = rvec[(2*m)*64 + c*2],   ai = rvec[(2*m)*64 + c*2 + 1];
    float br = rvec[(2*m+1)*64 + c*2], bi = rvec[(2*m+1)*64 + c*2 + 1];
    float na = rsqrtf(ar*ar + ai*ai); ar *= na; ai *= na;
    float nb = rsqrtf(br*br + bi*bi); br *= nb; bi *= nb;
    float* f = fr + m*128;
    f[c*2]        = br*ar - bi*ai;   // p=0 (composed rotor)
    f[c*2 + 1]    = br*ai + bi*ar;
    f[64 + c*2]   = br;              // p=1
    f[64 + c*2+1] = bi;
  }
}

// ---------------------------------------------------------------------------
// K2: per-edge, 16 lanes/edge. Coalesced bf16 row gathers, full-line eft
// stores (packed cvt), a2-only shfl reduction, precomputed a1c gather.
// ---------------------------------------------------------------------------
__global__ __launch_bounds__(256) void edge_kernel(
    const u16* __restrict__ featb, const int* __restrict__ inst,
    const float* __restrict__ fr, const float* __restrict__ a1c,
    const float* __restrict__ attn2, u16* __restrict__ eft,
    float* __restrict__ a_ws, int* __restrict__ cnt, int* __restrict__ bucket,
    int E, int N)
{
  __shared__ float frs[128];
  __shared__ float w2s[256];
  int m = blockIdx.y;
  int t = threadIdx.x;
  if (t < 128) frs[t] = fr[m*128 + t];
  w2s[t] = attn2[t];
  __syncthreads();

  int g = t >> 4, l = t & 15;           // group = edge, lane-in-group = 4 channels
  int e = blockIdx.x * 16 + g;
  if (e >= E) return;
  int base = (m*E + e)*3;
  int i0 = inst[base], i1 = inst[base+1], i2 = inst[base+2];

  const uint2* fb = (const uint2*)featb;             // 4 bf16 per uint2, 16/row
  uint2 v0 = fb[(size_t)i0*16 + l];
  uint2 v1 = fb[(size_t)i1*16 + l];
  uint2 v2 = fb[(size_t)i2*16 + l];
  float f0[4], f1[4], f2v[4];
  up2(v0.x, f0[0], f0[1]); up2(v0.y, f0[2], f0[3]);
  up2(v1.x, f1[0], f1[1]); up2(v1.y, f1[2], f1[3]);
  up2(v2.x, f2v[0], f2v[1]); up2(v2.y, f2v[2], f2v[3]);

  float4 R0 = *(const float4*)&frs[4*l];        // (Re c0, Im c0, Re c1, Im c1)
  float4 R1 = *(const float4*)&frs[64 + 4*l];

  float mre0 = (f0[0]*R0.x - f0[1]*R0.y + f1[0]*R1.x - f1[1]*R1.y + f2v[0]) * (1.f/3.f);
  float mim0 = (f0[0]*R0.y + f0[1]*R0.x + f1[0]*R1.y + f1[1]*R1.x + f2v[1]) * (1.f/3.f);
  float mre1 = (f0[2]*R0.z - f0[3]*R0.w + f1[2]*R1.z - f1[3]*R1.w + f2v[2]) * (1.f/3.f);
  float mim1 = (f0[2]*R0.w + f0[3]*R0.z + f1[2]*R1.w + f1[3]*R1.z + f2v[3]) * (1.f/3.f);

  float ef[4], s;
  s = celu3(mre0) * sigm(mre0); ef[0] = celu3(s);
  s = celu3(mim0) * sigm(mim0); ef[1] = celu3(s);
  s = celu3(mre1) * sigm(mre1); ef[2] = celu3(s);
  s = celu3(mim1) * sigm(mim1); ef[3] = celu3(s);

  uint2 uo;
  uo.x = pk2(ef[0], ef[1]);
  uo.y = pk2(ef[2], ef[3]);
  ((uint2*)eft)[(size_t)(m*E + e)*16 + l] = uo;   // wave: 4 edges x 128B contiguous

  float d2[4];
  #pragma unroll
  for (int k = 0; k < 4; ++k){
    int wb = k*64 + l*4;
    d2[k] = ef[0]*w2s[wb] + ef[1]*w2s[wb+1] + ef[2]*w2s[wb+2] + ef[3]*w2s[wb+3];
  }
  #pragma unroll
  for (int off = 8; off; off >>= 1){
    #pragma unroll
    for (int k = 0; k < 4; ++k) d2[k] += __shfl_xor(d2[k], off);
  }
  if (l == 0){
    float4 a1v = ((const float4*)a1c)[i0];   // celu3(a1) precomputed per node
    float4 av;
    av.x = celu3(a1v.x + d2[0]);
    av.y = celu3(a1v.y + d2[1]);
    av.z = celu3(a1v.z + d2[2]);
    av.w = celu3(a1v.w + d2[3]);
    ((float4*)a_ws)[m*E + e] = av;
    int pos = atomicAdd(&cnt[m*N + i0], 1);
    if (pos < CAP) bucket[(size_t)(m*N + i0)*CAP + pos] = e;
  }
}

// ---------------------------------------------------------------------------
// K3: one wave per (segment, path), lane-parallel softmax WITHOUT reduction
// trees: exp(a) is safe un-shifted (|a| <= ~7 by construction), and the
// denominator is accumulated from the already-broadcast weights in phase 2.
// softmax(a) == softmax(a - amax) exactly (ratio identity).
// ---------------------------------------------------------------------------
__global__ __launch_bounds__(256) void seg_kernel(
    const float* __restrict__ a_ws, const u16* __restrict__ eft,
    const int* __restrict__ cnt, const int* __restrict__ bucket,
    u16* __restrict__ z, int E, int N)
{
  int m = blockIdx.y;
  int n = blockIdx.x * 4 + (threadIdx.x >> 6);
  if (n >= N) return;
  int lane = threadIdx.x & 63;
  int sidx = m*N + n;
  int deg = cnt[sidx]; if (deg > CAP) deg = CAP;

  float h0=0.f, h1=0.f, h2=0.f, h3=0.f;
  float d0=0.f, d1=0.f, d2=0.f, d3=0.f;
  if (deg > 0){
    const int* bk = bucket + (size_t)sidx * CAP;
    size_t ebase = (size_t)m * E;

    // lane j <- edge j: coalesced bucket read + 16B a gather + one exp
    int e = (lane < deg) ? bk[lane] : 0;
    float w0 = 0.f, w1 = 0.f, w2 = 0.f, w3 = 0.f;
    if (lane < deg){
      float4 av = ((const float4*)a_ws)[ebase + e];
      w0 = fexp(av.x); w1 = fexp(av.y); w2 = fexp(av.z); w3 = fexp(av.w);
    }

    // phase 2: weighted sum of eft rows (coalesced 128B row per iter);
    // denominators accumulate from the broadcast weights (no shfl tree).
    const u16* ep = eft + ebase*64;
    for (int j = 0; j < deg; ++j){
      int   ej  = __shfl(e,  j);
      float a0j = __shfl(w0, j), a1j = __shfl(w1, j);
      float a2j = __shfl(w2, j), a3j = __shfl(w3, j);
      float ev = b2f(ep[(size_t)ej*64 + lane]);
      h0 += a0j*ev; h1 += a1j*ev; h2 += a2j*ev; h3 += a3j*ev;
      d0 += a0j;    d1 += a1j;    d2 += a2j;    d3 += a3j;
    }
    h0 /= d0; h1 /= d1; h2 /= d2; h3 /= d3;
  }
  u16* zr = z + (size_t)sidx*256 + lane;
  zr[0]   = f2b(celu3(h0));
  zr[64]  = f2b(celu3(h1));
  zr[128] = f2b(celu3(h2));
  zr[192] = f2b(celu3(h3));
}

// ---------------------------------------------------------------------------
// K4: fused 3-layer MLP (MFMA bf16), 64 rows/block.
// LDS: t2 tile overlays the z/t1 tile (barrier-separated) -> 34 KB, 4 blocks/CU.
// Weight B-fragments software-pipelined (next-ks prefetch in registers).
// ---------------------------------------------------------------------------
__global__ __launch_bounds__(256, 4) void mlp_kernel(
    const u16* __restrict__ z, const u16* __restrict__ fw1b, const float* __restrict__ fb1,
    const u16* __restrict__ fw2b, const float* __restrict__ fb2, const float* __restrict__ fw3,
    float* __restrict__ wacc, int rows, int N)
{
  __shared__ u16 buf[64][264];   // z tile -> t1 tile -> (overlaid) t2 tile
  __shared__ float fw3s[128];
  __shared__ float sArr[64];
  u16 (*t2t)[136] = (u16 (*)[136])&buf[0][0];
  int tid = threadIdx.x;
  int row0 = blockIdx.x * 64;

  if (tid < 128) fw3s[tid] = fw3[tid];

  // stage z (bf16 global) -> LDS; rows past `rows` zeroed
  const uint4* zg = (const uint4*)z;     // 8 bf16 per uint4, 32 per row
  #pragma unroll
  for (int it = 0; it < 8; ++it){
    int idx = it*256 + tid;
    int row = idx >> 5;
    int c8  = idx & 31;
    uint4 v = make_uint4(0u,0u,0u,0u);
    int gr = row0 + row;
    if (gr < rows) v = zg[(size_t)gr*32 + c8];
    *(uint4*)&buf[row][c8*8] = v;
  }
  __syncthreads();

  int wv = tid >> 6, lane = tid & 63, lr = lane & 15, quad = lane >> 4;
  f32x4 zero4 = {0.f, 0.f, 0.f, 0.f};

  // ---- layer 1: t1(64x256) = celu3(z @ fw1^T + fb1); wave wv owns cols [64wv,64wv+64)
  f32x4 acc[4][4];
  #pragma unroll
  for (int a = 0; a < 4; ++a)
    #pragma unroll
    for (int b = 0; b < 4; ++b) acc[a][b] = zero4;

  const u16* wb1 = fw1b + (size_t)(wv*64 + lr)*256 + quad*8;
  bf16x8 bfr[4], bnx[4];
  #pragma unroll
  for (int nt = 0; nt < 4; ++nt) bfr[nt] = *(const bf16x8*)(wb1 + nt*16*256);
  #pragma unroll
  for (int ks = 0; ks < 8; ++ks){
    if (ks < 7){
      #pragma unroll
      for (int nt = 0; nt < 4; ++nt)
        bnx[nt] = *(const bf16x8*)(wb1 + nt*16*256 + (ks+1)*32);
    }
    #pragma unroll
    for (int mt = 0; mt < 4; ++mt){
      bf16x8 af = *(const bf16x8*)&buf[mt*16 + lr][ks*32 + quad*8];
      #pragma unroll
      for (int nt = 0; nt < 4; ++nt)
        acc[mt][nt] = __builtin_amdgcn_mfma_f32_16x16x32_bf16(af, bfr[nt], acc[mt][nt], 0, 0, 0);
    }
    #pragma unroll
    for (int nt = 0; nt < 4; ++nt) bfr[nt] = bnx[nt];
  }
  __syncthreads();   // all z reads done before overwriting buf with t1
  #pragma unroll
  for (int nt = 0; nt < 4; ++nt){
    int col = wv*64 + nt*16 + lr;
    float bias = fb1[col];
    #pragma unroll
    for (int mt = 0; mt < 4; ++mt)
      #pragma unroll
      for (int ri = 0; ri < 4; ++ri){
        int row = mt*16 + quad*4 + ri;      // C/D: col=lane&15, row=(lane>>4)*4+reg
        buf[row][col] = f2b(celu3(acc[mt][nt][ri] + bias));
      }
  }
  __syncthreads();

  // ---- layer 2: t2(64x128) = celu3(t1 @ fw2^T + fb2); wave wv owns cols [32wv,32wv+32)
  f32x4 acc2[4][2];
  #pragma unroll
  for (int a = 0; a < 4; ++a){ acc2[a][0] = zero4; acc2[a][1] = zero4; }
  const u16* wb2 = fw2b + (size_t)(wv*32 + lr)*256 + quad*8;
  bf16x8 cfr[2], cnx[2];
  cfr[0] = *(const bf16x8*)(wb2);
  cfr[1] = *(const bf16x8*)(wb2 + 16*256);
  #pragma unroll
  for (int ks = 0; ks < 8; ++ks){
    if (ks < 7){
      cnx[0] = *(const bf16x8*)(wb2 + (ks+1)*32);
      cnx[1] = *(const bf16x8*)(wb2 + 16*256 + (ks+1)*32);
    }
    #pragma unroll
    for (int mt = 0; mt < 4; ++mt){
      bf16x8 af = *(const bf16x8*)&buf[mt*16 + lr][ks*32 + quad*8];
      acc2[mt][0] = __builtin_amdgcn_mfma_f32_16x16x32_bf16(af, cfr[0], acc2[mt][0], 0, 0, 0);
      acc2[mt][1] = __builtin_amdgcn_mfma_f32_16x16x32_bf16(af, cfr[1], acc2[mt][1], 0, 0, 0);
    }
    cfr[0] = cnx[0]; cfr[1] = cnx[1];
  }
  __syncthreads();   // all t1 reads done before overlaying buf with t2
  #pragma unroll
  for (int nt = 0; nt < 2; ++nt){
    int col = wv*32 + nt*16 + lr;
    float bias = fb2[col];
    #pragma unroll
    for (int mt = 0; mt < 4; ++mt)
      #pragma unroll
      for (int ri = 0; ri < 4; ++ri)
        t2t[mt*16 + quad*4 + ri][col] = f2b(celu3(acc2[mt][nt][ri] + bias));
  }
  __syncthreads();

  // ---- layer 3: s_r = t2[r,:] . fw3 ; 4 threads per row
  int r = tid >> 2, q = tid & 3;
  float p = 0.f;
  #pragma unroll
  for (int j = 0; j < 32; ++j){
    int jj = q*32 + j;
    p += b2f(t2t[r][jj]) * fw3s[jj];
  }
  p += __shfl_xor(p, 1);
  p += __shfl_xor(p, 2);
  if (q == 0) sArr[r] = p;
  __syncthreads();

  if (tid < 64){
    int gr = row0 + tid;
    float s  = (gr < rows) ? sArr[tid] : 0.f;
    float s0 = (gr < N) ? s : 0.f;      // path-0 rows are sidx < N
    float s1 = (gr < N) ? 0.f : s;
    #pragma unroll
    for (int off = 32; off; off >>= 1){
      s0 += __shfl_xor(s0, off);
      s1 += __shfl_xor(s1, off);
    }
    if (tid == 0){
      atomicAdd(&wacc[0], s0);
      atomicAdd(&wacc[1], s1);
    }
  }
}

// ---------------------------------------------------------------------------
// K5a: beta = softmax(w / N) over the 2 paths
// ---------------------------------------------------------------------------
__global__ void beta_kernel(float* __restrict__ wacc, float invN){
  if (threadIdx.x == 0 && blockIdx.x == 0){
    float w0 = wacc[0]*invN, w1 = wacc[1]*invN;
    float mx = fmaxf(w0, w1);
    float e0 = __expf(w0 - mx), e1 = __expf(w1 - mx);
    float s = e0 + e1;
    wacc[2] = e0 / s;
    wacc[3] = e1 / s;
  }
}

// ---------------------------------------------------------------------------
// K5b: out = beta0*z0 + beta1*z1 -> fp32
// ---------------------------------------------------------------------------
__global__ __launch_bounds__(256) void out_kernel(
    const u16* __restrict__ z, const float* __restrict__ wacc,
    float* __restrict__ out, int total)   // total = N*256
{
  int idx = blockIdx.x * 256 + threadIdx.x;   // one uint4 (8 bf16) per thread
  if (idx*8 >= total) return;
  float b0 = wacc[2], b1 = wacc[3];
  uint4 u0 = ((const uint4*)z)[idx];
  uint4 u1 = ((const uint4*)z)[(total >> 3) + idx];
  float a0,a1v,c0,c1;
  float4 o;
  up2(u0.x, a0, a1v); up2(u1.x, c0, c1);
  o.x = b0*a0 + b1*c0; o.y = b0*a1v + b1*c1;
  up2(u0.y, a0, a1v); up2(u1.y, c0, c1);
  o.z = b0*a0 + b1*c0; o.w = b0*a1v + b1*c1;
  ((float4*)out)[idx*2] = o;
  up2(u0.z, a0, a1v); up2(u1.z, c0, c1);
  o.x = b0*a0 + b1*c0; o.y = b0*a1v + b1*c1;
  up2(u0.w, a0, a1v); up2(u1.w, c0, c1);
  o.z = b0*a0 + b1*c0; o.w = b0*a1v + b1*c1;
  ((float4*)out)[idx*2 + 1] = o;
}

// ---------------------------------------------------------------------------
extern "C" void kernel_launch(void* const* d_in, const int* in_sizes, int n_in,
                              void* d_out, int out_size, void* d_ws, size_t ws_size,
                              hipStream_t stream)
{
  (void)n_in; (void)out_size; (void)ws_size;
  const float* feat  = (const float*)d_in[0];
  const float* rvec  = (const float*)d_in[1];
  const float* attn1 = (const float*)d_in[2];
  const float* attn2 = (const float*)d_in[3];
  const float* fw1   = (const float*)d_in[4];
  const float* fb1   = (const float*)d_in[5];
  const float* fw2   = (const float*)d_in[6];
  const float* fb2   = (const float*)d_in[7];
  const float* fw3   = (const float*)d_in[8];
  const int*   inst  = (const int*)d_in[9];

  int N = in_sizes[0] / 64;       // 50000
  int E = in_sizes[9] / 6;        // 250000

  char* ws = (char*)d_ws;
  u16*   z      = (u16*)ws;                            size_t zB = (size_t)2*N*256*2;
  u16*   eft    = (u16*)(ws + zB);                     size_t eB = (size_t)2*E*64*2;
  float* a_ws   = (float*)(ws + zB + eB);              size_t aB = (size_t)2*E*4*4;
  int*   bucket = (int*)(ws + zB + eB + aB);           size_t bB = (size_t)2*N*CAP*4;
  int*   cnt    = (int*)(ws + zB + eB + aB + bB);      size_t cB = (size_t)2*N*4;
  u16*   featb  = (u16*)(ws + zB + eB + aB + bB + cB); size_t fB = (size_t)N*64*2;
  float* a1c    = (float*)(ws + zB + eB + aB + bB + cB + fB);  size_t a1B = (size_t)N*4*4;
  u16*   fw1b   = (u16*)(ws + zB + eB + aB + bB + cB + fB + a1B);
  u16*   fw2b   = fw1b + 256*256;
  float* fr     = (float*)(fw2b + 128*256);
  float* wacc   = fr + 256;

  hipMemsetAsync(cnt, 0, cB, stream);
  hipMemsetAsync(wacc, 0, 2*sizeof(float), stream);

  a1_kernel<<<(N + 15)/16, 256, 0, stream>>>(feat, attn1, featb, a1c, N);
  conv_kernel<<<(256*256/8 + 255)/256, 256, 0, stream>>>(fw1, fw1b, 256*256/8);
  conv_kernel<<<(128*256/8 + 255)/256, 256, 0, stream>>>(fw2, fw2b, 128*256/8);
  fr_kernel<<<1, 64, 0, stream>>>(rvec, fr);
  edge_kernel<<<dim3((E + 15)/16, 2), 256, 0, stream>>>(
      featb, inst, fr, a1c, attn2, eft, a_ws, cnt, bucket, E, N);
  seg_kernel<<<dim3((N + 3)/4, 2), 256, 0, stream>>>(a_ws, eft, cnt, bucket, z, E, N);
  mlp_kernel<<<(2*N + 63)/64, 256, 0, stream>>>(z, fw1b, fb1, fw2b, fb2, fw3, wacc, 2*N, N);
  beta_kernel<<<1, 64, 0, stream>>>(wacc, 1.f/(float)N);
  out_kernel<<<((N*256/8) + 255)/256, 256, 0, stream>>>(z, wacc, (float*)d_out, N*256);
}